// Round 11
// baseline (4582.999 us; speedup 1.0000x reference)
//
#include <hip/hip_runtime.h>
#include <hip/hip_bf16.h>

#define B_   64
#define T_   2048
#define H_   128
#define G_   384      // 3*H
#define D0_  18
#define WIN  4
#define RING 8
#define NW   (T_ / WIN)   // 512
#define HSTR 136          // h ring row stride in shorts

typedef __hip_bfloat16 bf16;
typedef __attribute__((ext_vector_type(4))) float f32x4;
typedef __attribute__((ext_vector_type(8))) short s16x8;

#define LOG2E 1.4426950408889634f
__device__ __forceinline__ float sigf(float x) {
    return __builtin_amdgcn_rcpf(1.0f + __builtin_amdgcn_exp2f(-LOG2E * x));
}
__device__ __forceinline__ float tanhf_(float x) {
    return 1.0f - 2.0f * __builtin_amdgcn_rcpf(1.0f + __builtin_amdgcn_exp2f((2.0f * LOG2E) * x));
}
__device__ __forceinline__ short f2bs(float v) {
    bf16 b = __float2bfloat16(v);
    return *reinterpret_cast<short*>(&b);
}

// ---------------------------------------------------------------------------
// xg0 GEMM: layer-0 input projection. C = x(131072 x 18) . W^T(384 x 18) + b,
// K padded to 32 for one 16x16x32 MFMA K-tile. Output in scan layout
// xg[((bg*T+t)*G + n)*16 + (b&15)], bf16. grid (1024, 3, ndir).
// ---------------------------------------------------------------------------
__global__ __launch_bounds__(256) void xg0_gemm(
    const float* __restrict__ x,
    const float* __restrict__ w_f, const float* __restrict__ w_r,
    const float* __restrict__ b_f, const float* __restrict__ b_r,
    bf16* __restrict__ xg_f, bf16* __restrict__ xg_r)
{
    __shared__ short As[128 * 40];
    __shared__ short Ws[128 * 40];
    __shared__ float Bias_s[128];

    const int dir  = blockIdx.z;
    const float* W    = dir ? w_r : w_f;
    const float* bias = dir ? b_r : b_f;
    bf16* xg          = dir ? xg_r : xg_f;

    const int tid  = threadIdx.x;
    const int lane = tid & 63;
    const int wv   = tid >> 6;
    const int col  = lane & 15;
    const int quad = lane >> 4;
    const int m0   = blockIdx.x * 128;
    const int n0   = blockIdx.y * 128;

    if (tid < 128) Bias_s[tid] = bias[n0 + tid];
    {
        const int row  = tid & 127;
        const int half = tid >> 7;          // 0/1 -> k 0..15 / 16..31
        #pragma unroll
        for (int i = 0; i < 16; ++i) {
            const int k = half * 16 + i;
            const float av = (k < D0_) ? x[(size_t)(m0 + row) * D0_ + k] : 0.0f;
            As[row * 40 + k] = f2bs(av);
            const float wvv = (k < D0_) ? W[(size_t)(n0 + row) * D0_ + k] : 0.0f;
            Ws[row * 40 + k] = f2bs(wvv);
        }
    }
    __syncthreads();

    s16x8 afr[2], bfr[8];
    #pragma unroll
    for (int mt = 0; mt < 2; ++mt)
        afr[mt] = *(const s16x8*)&As[(wv * 32 + mt * 16 + col) * 40 + quad * 8];
    #pragma unroll
    for (int nt = 0; nt < 8; ++nt)
        bfr[nt] = *(const s16x8*)&Ws[(nt * 16 + col) * 40 + quad * 8];

    f32x4 acc[2][8];
    #pragma unroll
    for (int mt = 0; mt < 2; ++mt)
        #pragma unroll
        for (int nt = 0; nt < 8; ++nt) {
            acc[mt][nt] = (f32x4){0.f, 0.f, 0.f, 0.f};
            acc[mt][nt] = __builtin_amdgcn_mfma_f32_16x16x32_bf16(
                afr[mt], bfr[nt], acc[mt][nt], 0, 0, 0);
        }

    #pragma unroll
    for (int mt = 0; mt < 2; ++mt) {
        #pragma unroll
        for (int nt = 0; nt < 8; ++nt) {
            const int n_g = n0 + nt * 16 + col;
            const float bv = Bias_s[nt * 16 + col];
            #pragma unroll
            for (int r = 0; r < 4; ++r) {
                const int m_g = m0 + wv * 32 + mt * 16 + quad * 4 + r;
                const int b = m_g >> 11, t = m_g & 2047;
                const size_t off = (((size_t)(b >> 4) * T_ + t) * G_ + n_g) * 16 + (b & 15);
                xg[off] = __float2bfloat16(acc[mt][nt][r] + bv);
            }
        }
    }
}

// ---------------------------------------------------------------------------
// xg1 GEMM (as R10): C(131072x384) = A(131072x256 bf16) . W^T(384x256 fp32)+b,
// scan layout output. grid (1024, 3, ndir).
// ---------------------------------------------------------------------------
__global__ __launch_bounds__(256, 2) void xg_gemm_mfma(
    const bf16* __restrict__ A,
    const float* __restrict__ w_f, const float* __restrict__ w_r,
    const float* __restrict__ b_f, const float* __restrict__ b_r,
    bf16* __restrict__ xg_f, bf16* __restrict__ xg_r)
{
    __shared__ short As[128 * 40];
    __shared__ short Ws[128 * 40];
    __shared__ float Bias_s[128];

    const int dir  = blockIdx.z;
    const float* W    = dir ? w_r : w_f;
    const float* bias = dir ? b_r : b_f;
    bf16* xg          = dir ? xg_r : xg_f;

    const int tid  = threadIdx.x;
    const int lane = tid & 63;
    const int wv   = tid >> 6;
    const int m0   = blockIdx.x * 128;
    const int n0   = blockIdx.y * 128;

    if (tid < 128) Bias_s[tid] = bias[n0 + tid];

    f32x4 acc[2][8];
    #pragma unroll
    for (int mt = 0; mt < 2; ++mt)
        #pragma unroll
        for (int nt = 0; nt < 8; ++nt) acc[mt][nt] = (f32x4){0.f, 0.f, 0.f, 0.f};

    for (int k0 = 0; k0 < 256; k0 += 32) {
        #pragma unroll
        for (int i = 0; i < 2; ++i) {
            const int c = tid + i * 256;
            const int row = c >> 2, quad = c & 3;
            *(uint4*)&As[row * 40 + quad * 8] =
                *(const uint4*)(A + (size_t)(m0 + row) * 256 + k0 + quad * 8);
        }
        #pragma unroll
        for (int i = 0; i < 4; ++i) {
            const int c = tid + i * 256;
            const int row = c >> 3, q = c & 7;
            const float4 v = *(const float4*)(W + (size_t)(n0 + row) * 256 + k0 + q * 4);
            ushort4 u;
            u.x = (unsigned short)f2bs(v.x); u.y = (unsigned short)f2bs(v.y);
            u.z = (unsigned short)f2bs(v.z); u.w = (unsigned short)f2bs(v.w);
            *(ushort4*)&Ws[row * 40 + q * 4] = u;
        }
        __syncthreads();

        s16x8 afr[2], bfr[8];
        #pragma unroll
        for (int mt = 0; mt < 2; ++mt)
            afr[mt] = *(const s16x8*)&As[(wv * 32 + mt * 16 + (lane & 15)) * 40 + (lane >> 4) * 8];
        #pragma unroll
        for (int nt = 0; nt < 8; ++nt)
            bfr[nt] = *(const s16x8*)&Ws[(nt * 16 + (lane & 15)) * 40 + (lane >> 4) * 8];

        #pragma unroll
        for (int mt = 0; mt < 2; ++mt)
            #pragma unroll
            for (int nt = 0; nt < 8; ++nt)
                acc[mt][nt] = __builtin_amdgcn_mfma_f32_16x16x32_bf16(
                    afr[mt], bfr[nt], acc[mt][nt], 0, 0, 0);
        __syncthreads();
    }

    #pragma unroll
    for (int mt = 0; mt < 2; ++mt) {
        #pragma unroll
        for (int nt = 0; nt < 8; ++nt) {
            const int n_g = n0 + nt * 16 + (lane & 15);
            const float bv = Bias_s[nt * 16 + (lane & 15)];
            #pragma unroll
            for (int r = 0; r < 4; ++r) {
                const int m_g = m0 + wv * 32 + mt * 16 + (lane >> 4) * 4 + r;
                const int b = m_g >> 11, t = m_g & 2047;
                const size_t off = (((size_t)(b >> 4) * T_ + t) * G_ + n_g) * 16 + (b & 15);
                xg[off] = __float2bfloat16(acc[mt][nt][r] + bv);
            }
        }
    }
}

// ---------------------------------------------------------------------------
// Unified GRU scan (both layers): r = sig(xg_r + hR + c_r), z likewise,
// n = tanh(xg_n + r*(hN + c_n)), h' = n + z*(h - n). xg includes b_ih.
// 8 WGs (dir, bg) x 512 thr. BARRIER-FREE step loop: waves sync via an LDS
// monotonic counter (ds_add + spin ds_read) after an LDS-only fence, so
// in-flight global loads/stores never drain on the step path.
// ---------------------------------------------------------------------------
__global__ __launch_bounds__(512) void gru_scan(
    const bf16* __restrict__ xg_f, const bf16* __restrict__ xg_r,
    const float* __restrict__ whh_f, const float* __restrict__ bhh_f,
    const float* __restrict__ whh_r, const float* __restrict__ bhh_r,
    bf16* __restrict__ hout, int fixed_dir)
{
    __shared__ __align__(16) bf16 hring[RING][16 * HSTR];
    __shared__ unsigned syncnt;

    const int bx   = blockIdx.x;
    const int dir  = (fixed_dir >= 0) ? fixed_dir : (bx >> 2);
    const int bg   = bx & 3;
    const int b0   = bg * 16;
    const int tid  = threadIdx.x;
    const int lane = tid & 63;
    const int wv   = tid >> 6;
    const int col  = lane & 15;
    const int quad = lane >> 4;
    const int jcol = wv * 16 + col;

    const bf16*  XG  = dir ? xg_r : xg_f;
    const float* Whh = dir ? whh_r : whh_f;
    const float* Bhh = dir ? bhh_r : bhh_f;

    s16x8 bfr[3][4];
    #pragma unroll
    for (int g = 0; g < 3; ++g) {
        const float* wrow = Whh + (size_t)(g * H_ + jcol) * H_;
        #pragma unroll
        for (int kt = 0; kt < 4; ++kt) {
            const float* p = wrow + kt * 32 + quad * 8;
            s16x8 f;
            #pragma unroll
            for (int i = 0; i < 8; ++i) f[i] = f2bs(p[i]);
            bfr[g][kt] = f;
        }
    }
    const float cr  = Bhh[jcol];
    const float cz  = Bhh[H_ + jcol];
    const float cnh = Bhh[2*H_ + jcol];

    for (int i = tid; i < 16 * HSTR; i += 512) hring[0][i] = __float2bfloat16(0.0f);
    if (tid == 0) syncnt = 0;

    const bf16* xgb = XG + (size_t)bg * T_ * G_ * 16;
    const size_t xo0 = ((size_t)0 * H_ + jcol) * 16 + quad * 4;
    const size_t xo1 = ((size_t)1 * H_ + jcol) * 16 + quad * 4;
    const size_t xo2 = ((size_t)2 * H_ + jcol) * 16 + quad * 4;

    uint2 xcur[WIN][3], xnxt[WIN][3];
    #pragma unroll
    for (int si = 0; si < WIN; ++si) {
        const int t = dir ? (T_ - 1 - si) : si;
        const size_t base = (size_t)t * G_ * 16;
        xcur[si][0] = *(const uint2*)(xgb + base + xo0);
        xcur[si][1] = *(const uint2*)(xgb + base + xo1);
        xcur[si][2] = *(const uint2*)(xgb + base + xo2);
    }
    __syncthreads();   // once: hring[0] + syncnt visible

    float hprev[4] = {0.f, 0.f, 0.f, 0.f};
    const f32x4 z4 = (f32x4){0.f, 0.f, 0.f, 0.f};

    for (int w = 0; w < NW; ++w) {
        #pragma unroll
        for (int si = 0; si < WIN; ++si) {
            const int s  = w * WIN + si;
            const int rb = s & (RING - 1);
            const int wb = (s + 1) & (RING - 1);

            if (si == 0 && w + 1 < NW) {
                #pragma unroll
                for (int sj = 0; sj < WIN; ++sj) {
                    const int s2 = (w + 1) * WIN + sj;
                    const int t2 = dir ? (T_ - 1 - s2) : s2;
                    const size_t base = (size_t)t2 * G_ * 16;
                    xnxt[sj][0] = *(const uint2*)(xgb + base + xo0);
                    xnxt[sj][1] = *(const uint2*)(xgb + base + xo1);
                    xnxt[sj][2] = *(const uint2*)(xgb + base + xo2);
                }
            }

            s16x8 afr[4];
            #pragma unroll
            for (int kt = 0; kt < 4; ++kt)
                afr[kt] = *(const s16x8*)&hring[rb][col * HSTR + kt * 32 + quad * 8];

            f32x4 aR0 = z4, aR1 = z4, aZ0 = z4, aZ1 = z4, aN0 = z4, aN1 = z4;
            aR0 = __builtin_amdgcn_mfma_f32_16x16x32_bf16(afr[0], bfr[0][0], aR0, 0, 0, 0);
            aZ0 = __builtin_amdgcn_mfma_f32_16x16x32_bf16(afr[0], bfr[1][0], aZ0, 0, 0, 0);
            aN0 = __builtin_amdgcn_mfma_f32_16x16x32_bf16(afr[0], bfr[2][0], aN0, 0, 0, 0);
            aR1 = __builtin_amdgcn_mfma_f32_16x16x32_bf16(afr[2], bfr[0][2], aR1, 0, 0, 0);
            aZ1 = __builtin_amdgcn_mfma_f32_16x16x32_bf16(afr[2], bfr[1][2], aZ1, 0, 0, 0);
            aN1 = __builtin_amdgcn_mfma_f32_16x16x32_bf16(afr[2], bfr[2][2], aN1, 0, 0, 0);
            aR0 = __builtin_amdgcn_mfma_f32_16x16x32_bf16(afr[1], bfr[0][1], aR0, 0, 0, 0);
            aZ0 = __builtin_amdgcn_mfma_f32_16x16x32_bf16(afr[1], bfr[1][1], aZ0, 0, 0, 0);
            aN0 = __builtin_amdgcn_mfma_f32_16x16x32_bf16(afr[1], bfr[2][1], aN0, 0, 0, 0);
            aR1 = __builtin_amdgcn_mfma_f32_16x16x32_bf16(afr[3], bfr[0][3], aR1, 0, 0, 0);
            aZ1 = __builtin_amdgcn_mfma_f32_16x16x32_bf16(afr[3], bfr[1][3], aZ1, 0, 0, 0);
            aN1 = __builtin_amdgcn_mfma_f32_16x16x32_bf16(afr[3], bfr[2][3], aN1, 0, 0, 0);

            const uint2 xr2 = xcur[si][0], xz2 = xcur[si][1], xn2 = xcur[si][2];
            const unsigned xru[4] = {xr2.x << 16, xr2.x & 0xffff0000u,
                                     xr2.y << 16, xr2.y & 0xffff0000u};
            const unsigned xzu[4] = {xz2.x << 16, xz2.x & 0xffff0000u,
                                     xz2.y << 16, xz2.y & 0xffff0000u};
            const unsigned xnu[4] = {xn2.x << 16, xn2.x & 0xffff0000u,
                                     xn2.y << 16, xn2.y & 0xffff0000u};
            #pragma unroll
            for (int r = 0; r < 4; ++r) {
                const float rg = sigf(__uint_as_float(xru[r]) + aR0[r] + aR1[r] + cr);
                const float zg = sigf(__uint_as_float(xzu[r]) + aZ0[r] + aZ1[r] + cz);
                const float ng = tanhf_(__uint_as_float(xnu[r]) + rg * (aN0[r] + aN1[r] + cnh));
                const float hn = ng + zg * (hprev[r] - ng);
                hprev[r] = hn;
                hring[wb][(quad * 4 + r) * HSTR + jcol] = __float2bfloat16(hn);
            }

            // ---- barrier-free wave sync: LDS-only fence + counter ----
            __threadfence_block();     // drains LDS ops only (lgkmcnt)
            if (lane == 0)
                __hip_atomic_fetch_add(&syncnt, 1u, __ATOMIC_RELAXED,
                                       __HIP_MEMORY_SCOPE_WORKGROUP);
            const unsigned tgt = (unsigned)(s + 1) * 8u;
            while (__hip_atomic_load(&syncnt, __ATOMIC_ACQUIRE,
                                     __HIP_MEMORY_SCOPE_WORKGROUP) < tgt)
                __builtin_amdgcn_s_sleep(1);
        }

        // window flush: fire-and-forget global stores (never force-drained)
        #pragma unroll
        for (int k = 0; k < 2; ++k) {
            const int c  = tid + k * 512;
            const int dt = c >> 8, m = (c >> 4) & 15, j8 = c & 15;
            const int s  = w * WIN + dt;
            const int t  = dir ? (T_ - 1 - s) : s;
            const uint4 v = *(const uint4*)&hring[(s + 1) & (RING - 1)][m * HSTR + j8 * 8];
            *(uint4*)(hout + ((size_t)(b0 + m) * T_ + t) * 256 + dir * H_ + j8 * 8) = v;
        }
        #pragma unroll
        for (int si = 0; si < WIN; ++si) {
            xcur[si][0] = xnxt[si][0];
            xcur[si][1] = xnxt[si][1];
            xcur[si][2] = xnxt[si][2];
        }
    }
}

// ---------------------------------------------------------------------------
// FC epilogue: out[bt][c] = fc_b[c] + fc_w[c][:] . l1h[bt][:]
// ---------------------------------------------------------------------------
__global__ __launch_bounds__(256, 2) void fc_kernel(
    const bf16* __restrict__ h, const float* __restrict__ fcw,
    const float* __restrict__ fcb, float* __restrict__ out)
{
    __shared__ float w0[256], w1[256];
    const int tid = threadIdx.x;
    w0[tid] = fcw[tid];
    w1[tid] = fcw[256 + tid];
    __syncthreads();

    const size_t bt = (size_t)blockIdx.x * 256 + tid;
    const bf16* hp = h + bt * 256;
    float s0 = fcb[0], s1 = fcb[1];
    #pragma unroll 4
    for (int k8 = 0; k8 < 32; ++k8) {
        const uint4 u = *(const uint4*)(hp + k8 * 8);
        const unsigned uu[4] = {u.x, u.y, u.z, u.w};
        #pragma unroll
        for (int p = 0; p < 4; ++p) {
            const float v0 = __uint_as_float(uu[p] << 16);
            const float v1 = __uint_as_float(uu[p] & 0xffff0000u);
            const int k = k8 * 8 + p * 2;
            s0 = fmaf(w0[k], v0, s0);     s1 = fmaf(w1[k], v0, s1);
            s0 = fmaf(w0[k + 1], v1, s0); s1 = fmaf(w1[k + 1], v1, s1);
        }
    }
    out[bt * 2]     = s0;
    out[bt * 2 + 1] = s1;
}

extern "C" void kernel_launch(void* const* d_in, const int* in_sizes, int n_in,
                              void* d_out, int out_size, void* d_ws, size_t ws_size,
                              hipStream_t stream)
{
    if (n_in < 19) return;
    const float* x     = (const float*)d_in[0];
    const float* wih0  = (const float*)d_in[1];
    const float* whh0  = (const float*)d_in[2];
    const float* bih0  = (const float*)d_in[3];
    const float* bhh0  = (const float*)d_in[4];
    const float* wih0r = (const float*)d_in[5];
    const float* whh0r = (const float*)d_in[6];
    const float* bih0r = (const float*)d_in[7];
    const float* bhh0r = (const float*)d_in[8];
    const float* wih1  = (const float*)d_in[9];
    const float* whh1  = (const float*)d_in[10];
    const float* bih1  = (const float*)d_in[11];
    const float* bhh1  = (const float*)d_in[12];
    const float* wih1r = (const float*)d_in[13];
    const float* whh1r = (const float*)d_in[14];
    const float* bih1r = (const float*)d_in[15];
    const float* bhh1r = (const float*)d_in[16];
    const float* fcw   = (const float*)d_in[17];
    const float* fcb   = (const float*)d_in[18];
    float* out = (float*)d_out;

    const size_t nBT  = (size_t)B_ * T_;
    const size_t hh_b = nBT * 2 * H_ * sizeof(bf16);     // 64 MiB
    const size_t xg_b = nBT * G_ * sizeof(bf16);         // 96 MiB per dir
    const size_t xg_el = nBT * G_;

    if (ws_size >= hh_b + 2 * xg_b) {                    // 256 MiB path
        bf16* l0h = (bf16*)d_ws;
        bf16* xgf = (bf16*)((char*)d_ws + hh_b);
        bf16* xgr = xgf + xg_el;

        xg0_gemm<<<dim3(1024, 3, 2), dim3(256), 0, stream>>>(
            x, wih0, wih0r, bih0, bih0r, xgf, xgr);
        gru_scan<<<dim3(8), dim3(512), 0, stream>>>(
            xgf, xgr, whh0, bhh0, whh0r, bhh0r, l0h, -1);
        xg_gemm_mfma<<<dim3(1024, 3, 2), dim3(256), 0, stream>>>(
            l0h, wih1, wih1r, bih1, bih1r, xgf, xgr);
        gru_scan<<<dim3(8), dim3(512), 0, stream>>>(
            xgf, xgr, whh1, bhh1, whh1r, bhh1r, l0h, -1);   // l1h aliases l0h
        fc_kernel<<<dim3((int)(nBT / 256)), dim3(256), 0, stream>>>(l0h, fcw, fcb, out);
    } else if (ws_size >= 2 * hh_b + xg_b) {             // 224 MiB sequential
        bf16* l0h = (bf16*)d_ws;
        bf16* xg  = (bf16*)((char*)d_ws + hh_b);
        bf16* l1h = (bf16*)((char*)d_ws + hh_b + xg_b);

        xg0_gemm<<<dim3(1024, 3, 1), dim3(256), 0, stream>>>(
            x, wih0, wih0, bih0, bih0, xg, xg);
        gru_scan<<<dim3(4), dim3(512), 0, stream>>>(
            xg, xg, whh0, bhh0, whh0r, bhh0r, l0h, 0);
        xg0_gemm<<<dim3(1024, 3, 1), dim3(256), 0, stream>>>(
            x, wih0r, wih0r, bih0r, bih0r, xg, xg);
        gru_scan<<<dim3(4), dim3(512), 0, stream>>>(
            xg, xg, whh0, bhh0, whh0r, bhh0r, l0h, 1);
        xg_gemm_mfma<<<dim3(1024, 3, 1), dim3(256), 0, stream>>>(
            l0h, wih1, wih1, bih1, bih1, xg, xg);
        gru_scan<<<dim3(4), dim3(512), 0, stream>>>(
            xg, xg, whh1, bhh1, whh1r, bhh1r, l1h, 0);
        xg_gemm_mfma<<<dim3(1024, 3, 1), dim3(256), 0, stream>>>(
            l0h, wih1r, wih1r, bih1r, bih1r, xg, xg);
        gru_scan<<<dim3(4), dim3(512), 0, stream>>>(
            xg, xg, whh1, bhh1, whh1r, bhh1r, l1h, 1);
        fc_kernel<<<dim3((int)(nBT / 256)), dim3(256), 0, stream>>>(l1h, fcw, fcb, out);
    }
}

// Round 12
// 3927.951 us; speedup vs baseline: 1.1668x; 1.1668x over previous
//
#include <hip/hip_runtime.h>
#include <hip/hip_bf16.h>

#define B_   64
#define T_   2048
#define H_   128
#define G_   384      // 3*H
#define D0_  18
#define WIN  4
#define RING 8
#define NW   (T_ / WIN)   // 512
#define HSTR 136          // h ring row stride in shorts

typedef __hip_bfloat16 bf16;
typedef __attribute__((ext_vector_type(4))) float f32x4;
typedef __attribute__((ext_vector_type(8))) short s16x8;

#define LOG2E 1.4426950408889634f
__device__ __forceinline__ float sigf(float x) {
    return __builtin_amdgcn_rcpf(1.0f + __builtin_amdgcn_exp2f(-LOG2E * x));
}
__device__ __forceinline__ float tanhf_(float x) {
    return 1.0f - 2.0f * __builtin_amdgcn_rcpf(1.0f + __builtin_amdgcn_exp2f((2.0f * LOG2E) * x));
}
__device__ __forceinline__ short f2bs(float v) {
    bf16 b = __float2bfloat16(v);
    return *reinterpret_cast<short*>(&b);
}
#define MFMA16(A, B, C) __builtin_amdgcn_mfma_f32_16x16x32_bf16((A), (B), (C), 0, 0, 0)

// WG-level wave sync via LDS counter (no s_barrier -> no vmcnt(0) drain).
__device__ __forceinline__ void wave_sync(unsigned* cnt, int lane, unsigned tgt) {
    __threadfence_block();   // lgkmcnt(0): our LDS writes visible
    if (lane == 0)
        __hip_atomic_fetch_add(cnt, 1u, __ATOMIC_RELAXED, __HIP_MEMORY_SCOPE_WORKGROUP);
    while (__hip_atomic_load(cnt, __ATOMIC_ACQUIRE, __HIP_MEMORY_SCOPE_WORKGROUP) < tgt) {}
}

// ---------------------------------------------------------------------------
// Layer 0 scan: fused x-projection, accumulator-seeded biases.
// 8 WGs (dir = bx>>2, 16 batches each) x 512 thr (8 waves).
// ---------------------------------------------------------------------------
__global__ __launch_bounds__(512) void gru_l0_mfma(
    const float* __restrict__ x,
    const float* __restrict__ wih_f, const float* __restrict__ whh_f,
    const float* __restrict__ bih_f, const float* __restrict__ bhh_f,
    const float* __restrict__ wih_r, const float* __restrict__ whh_r,
    const float* __restrict__ bih_r, const float* __restrict__ bhh_r,
    bf16* __restrict__ l0h)
{
    __shared__ __align__(16) bf16 hring[RING][16 * HSTR];
    __shared__ __align__(16) bf16 xbuf[2][WIN][16][40];
    __shared__ unsigned syncnt;

    const int bx   = blockIdx.x;
    const int dir  = bx >> 2;
    const int bg   = bx & 3;
    const int b0   = bg * 16;
    const int tid  = threadIdx.x;
    const int lane = tid & 63;
    const int wv   = tid >> 6;
    const int col  = lane & 15;
    const int quad = lane >> 4;
    const int jcol = wv * 16 + col;

    const float* Wih = dir ? wih_r : wih_f;
    const float* Whh = dir ? whh_r : whh_f;
    const float* Bih = dir ? bih_r : bih_f;
    const float* Bhh = dir ? bhh_r : bhh_f;

    s16x8 bfr[3][4], bxf[3];
    #pragma unroll
    for (int g = 0; g < 3; ++g) {
        const float* wrow = Whh + (size_t)(g * H_ + jcol) * H_;
        #pragma unroll
        for (int kt = 0; kt < 4; ++kt) {
            const float* p = wrow + kt * 32 + quad * 8;
            s16x8 f;
            #pragma unroll
            for (int i = 0; i < 8; ++i) f[i] = f2bs(p[i]);
            bfr[g][kt] = f;
        }
        const float* xrow = Wih + (size_t)(g * H_ + jcol) * D0_;
        s16x8 fx;
        #pragma unroll
        for (int i = 0; i < 8; ++i) {
            const int k = quad * 8 + i;
            fx[i] = (k < D0_) ? f2bs(xrow[k]) : (short)0;
        }
        bxf[g] = fx;
    }
    // seeds (per-lane constants, broadcast to all 4 acc rows)
    const float crz0 = Bih[jcol]        + Bhh[jcol];
    const float crz1 = Bih[H_ + jcol]   + Bhh[H_ + jcol];
    const float bnx  = Bih[2*H_ + jcol];
    const float bnh  = Bhh[2*H_ + jcol];
    const f32x4 sR = (f32x4){crz0, crz0, crz0, crz0};
    const f32x4 sZ = (f32x4){crz1, crz1, crz1, crz1};
    const f32x4 sX = (f32x4){bnx, bnx, bnx, bnx};
    const f32x4 sN = (f32x4){bnh, bnh, bnh, bnh};
    const f32x4 z4 = (f32x4){0.f, 0.f, 0.f, 0.f};

    for (int i = tid; i < 16 * HSTR; i += 512) hring[0][i] = __float2bfloat16(0.0f);
    if (tid == 0) syncnt = 0;
    // stage x window 0 directly
    #pragma unroll
    for (int k = 0; k < 4; ++k) {
        const int i = tid + k * 512;
        const int si = i >> 9, m = (i >> 5) & 15, c = i & 31;
        const int t = dir ? (T_ - 1 - si) : si;
        const float v = (c < D0_) ? x[((size_t)(b0 + m) * T_ + t) * D0_ + c] : 0.0f;
        xbuf[0][si][m][c] = __float2bfloat16(v);
    }
    __syncthreads();

    float hprev[4] = {0.f, 0.f, 0.f, 0.f};
    float xv[4];

    for (int w = 0; w < NW; ++w) {
        const int par = w & 1;
        s16x8 axf[WIN];
        #pragma unroll
        for (int si = 0; si < WIN; ++si)
            axf[si] = *(const s16x8*)&xbuf[par][si][col][quad * 8];

        #pragma unroll
        for (int si = 0; si < WIN; ++si) {
            const int s  = w * WIN + si;
            const int rb = s & (RING - 1);
            const int wb = (s + 1) & (RING - 1);

            // issue next window's x loads early (consumed at si==3)
            if (si == 0 && w + 1 < NW) {
                #pragma unroll
                for (int k = 0; k < 4; ++k) {
                    const int i = tid + k * 512;
                    const int sj = i >> 9, m = (i >> 5) & 15, c = i & 31;
                    const int s2 = (w + 1) * WIN + sj;
                    const int t2 = dir ? (T_ - 1 - s2) : s2;
                    xv[k] = (c < D0_) ? x[((size_t)(b0 + m) * T_ + t2) * D0_ + c] : 0.0f;
                }
            }

            // x-MFMAs first (independent of ring read)
            f32x4 aR1 = MFMA16(axf[si], bxf[0], z4);
            f32x4 aZ1 = MFMA16(axf[si], bxf[1], z4);
            f32x4 aX  = MFMA16(axf[si], bxf[2], sX);

            s16x8 afr[4];
            #pragma unroll
            for (int kt = 0; kt < 4; ++kt)
                afr[kt] = *(const s16x8*)&hring[rb][col * HSTR + kt * 32 + quad * 8];

            f32x4 aR0 = MFMA16(afr[0], bfr[0][0], sR);
            f32x4 aZ0 = MFMA16(afr[0], bfr[1][0], sZ);
            f32x4 aN0 = MFMA16(afr[0], bfr[2][0], sN);
            aR1 = MFMA16(afr[2], bfr[0][2], aR1);
            aZ1 = MFMA16(afr[2], bfr[1][2], aZ1);
            f32x4 aN1 = MFMA16(afr[2], bfr[2][2], z4);
            aR0 = MFMA16(afr[1], bfr[0][1], aR0);
            aZ0 = MFMA16(afr[1], bfr[1][1], aZ0);
            aN0 = MFMA16(afr[1], bfr[2][1], aN0);
            aR1 = MFMA16(afr[3], bfr[0][3], aR1);
            aZ1 = MFMA16(afr[3], bfr[1][3], aZ1);
            aN1 = MFMA16(afr[3], bfr[2][3], aN1);

            #pragma unroll
            for (int r = 0; r < 4; ++r) {
                const float rg = sigf(aR0[r] + aR1[r]);
                const float zg = sigf(aZ0[r] + aZ1[r]);
                const float ng = tanhf_(fmaf(rg, aN0[r] + aN1[r], aX[r]));
                const float hn = fmaf(zg, hprev[r] - ng, ng);
                hprev[r] = hn;
                hring[wb][(quad * 4 + r) * HSTR + jcol] = __float2bfloat16(hn);
            }

            // stage next window's x into LDS (loads are ~3 steps old)
            if (si == 3 && w + 1 < NW) {
                #pragma unroll
                for (int k = 0; k < 4; ++k) {
                    const int i = tid + k * 512;
                    const int sj = i >> 9, m = (i >> 5) & 15, c = i & 31;
                    xbuf[par ^ 1][sj][m][c] = __float2bfloat16(xv[k]);
                }
            }
            wave_sync(&syncnt, lane, (unsigned)(s + 1) * 8u);
        }

        // flush h history (fire-and-forget stores, never force-drained)
        #pragma unroll
        for (int k = 0; k < 2; ++k) {
            const int c  = tid + k * 512;
            const int dt = c >> 8, m = (c >> 4) & 15, j8 = c & 15;
            const int s  = w * WIN + dt;
            const int t  = dir ? (T_ - 1 - s) : s;
            const uint4 v = *(const uint4*)&hring[(s + 1) & (RING - 1)][m * HSTR + j8 * 8];
            *(uint4*)(l0h + ((size_t)(b0 + m) * T_ + t) * 256 + dir * H_ + j8 * 8) = v;
        }
    }
}

// ---------------------------------------------------------------------------
// xg GEMM (both dirs, grid.z): C = l0h(131072x256 bf16) . W^T + bias, where
// bias = bih[n] + (n<256 ? bhh[n] : 0)  -- r,z biases folded in.
// Output layout xg[((bg*T+t)*G + n)*16 + (b&15)] bf16.
// ---------------------------------------------------------------------------
__global__ __launch_bounds__(256, 2) void xg_gemm_mfma(
    const bf16* __restrict__ A,
    const float* __restrict__ w_f, const float* __restrict__ w_r,
    const float* __restrict__ bi_f, const float* __restrict__ bi_r,
    const float* __restrict__ bh_f, const float* __restrict__ bh_r,
    bf16* __restrict__ xg_f, bf16* __restrict__ xg_r)
{
    __shared__ short As[128 * 40];
    __shared__ short Ws[128 * 40];
    __shared__ float Bias_s[128];

    const int dir  = blockIdx.z;
    const float* W   = dir ? w_r : w_f;
    const float* bi  = dir ? bi_r : bi_f;
    const float* bh  = dir ? bh_r : bh_f;
    bf16* xg         = dir ? xg_r : xg_f;

    const int tid  = threadIdx.x;
    const int lane = tid & 63;
    const int wv   = tid >> 6;
    const int m0   = blockIdx.x * 128;
    const int n0   = blockIdx.y * 128;

    if (tid < 128) {
        const int n = n0 + tid;
        Bias_s[tid] = bi[n] + ((n < 2 * H_) ? bh[n] : 0.0f);
    }

    f32x4 acc[2][8];
    #pragma unroll
    for (int mt = 0; mt < 2; ++mt)
        #pragma unroll
        for (int nt = 0; nt < 8; ++nt) acc[mt][nt] = (f32x4){0.f, 0.f, 0.f, 0.f};

    for (int k0 = 0; k0 < 256; k0 += 32) {
        #pragma unroll
        for (int i = 0; i < 2; ++i) {
            const int c = tid + i * 256;
            const int row = c >> 2, quad = c & 3;
            *(uint4*)&As[row * 40 + quad * 8] =
                *(const uint4*)(A + (size_t)(m0 + row) * 256 + k0 + quad * 8);
        }
        #pragma unroll
        for (int i = 0; i < 4; ++i) {
            const int c = tid + i * 256;
            const int row = c >> 3, q = c & 7;
            const float4 v = *(const float4*)(W + (size_t)(n0 + row) * 256 + k0 + q * 4);
            ushort4 u;
            u.x = (unsigned short)f2bs(v.x); u.y = (unsigned short)f2bs(v.y);
            u.z = (unsigned short)f2bs(v.z); u.w = (unsigned short)f2bs(v.w);
            *(ushort4*)&Ws[row * 40 + q * 4] = u;
        }
        __syncthreads();

        s16x8 afr[2], bfr[8];
        #pragma unroll
        for (int mt = 0; mt < 2; ++mt)
            afr[mt] = *(const s16x8*)&As[(wv * 32 + mt * 16 + (lane & 15)) * 40 + (lane >> 4) * 8];
        #pragma unroll
        for (int nt = 0; nt < 8; ++nt)
            bfr[nt] = *(const s16x8*)&Ws[(nt * 16 + (lane & 15)) * 40 + (lane >> 4) * 8];

        #pragma unroll
        for (int mt = 0; mt < 2; ++mt)
            #pragma unroll
            for (int nt = 0; nt < 8; ++nt)
                acc[mt][nt] = MFMA16(afr[mt], bfr[nt], acc[mt][nt]);
        __syncthreads();
    }

    #pragma unroll
    for (int mt = 0; mt < 2; ++mt) {
        #pragma unroll
        for (int nt = 0; nt < 8; ++nt) {
            const int n_g = n0 + nt * 16 + (lane & 15);
            const float bv = Bias_s[nt * 16 + (lane & 15)];
            #pragma unroll
            for (int r = 0; r < 4; ++r) {
                const int m_g = m0 + wv * 32 + mt * 16 + (lane >> 4) * 4 + r;
                const int b = m_g >> 11, t = m_g & 2047;
                const size_t off = (((size_t)(b >> 4) * T_ + t) * G_ + n_g) * 16 + (b & 15);
                xg[off] = __float2bfloat16(acc[mt][nt][r] + bv);
            }
        }
    }
}

// ---------------------------------------------------------------------------
// Layer 1 scan: xg register-prefetched; accumulators seeded with unpacked xg
// (r,z incl. all biases) and bhh_n. Unpack happens pre-MFMA (off-chain).
// ---------------------------------------------------------------------------
__global__ __launch_bounds__(512) void gru_l1_mfma(
    const bf16* __restrict__ xg_f, const bf16* __restrict__ xg_r,
    const float* __restrict__ whh_f, const float* __restrict__ bhh_f,
    const float* __restrict__ whh_r, const float* __restrict__ bhh_r,
    bf16* __restrict__ l1h, int fixed_dir)
{
    __shared__ __align__(16) bf16 hring[RING][16 * HSTR];
    __shared__ unsigned syncnt;

    const int bx   = blockIdx.x;
    const int dir  = (fixed_dir >= 0) ? fixed_dir : (bx >> 2);
    const int bg   = bx & 3;
    const int b0   = bg * 16;
    const int tid  = threadIdx.x;
    const int lane = tid & 63;
    const int wv   = tid >> 6;
    const int col  = lane & 15;
    const int quad = lane >> 4;
    const int jcol = wv * 16 + col;

    const bf16*  XG  = dir ? xg_r : xg_f;
    const float* Whh = dir ? whh_r : whh_f;
    const float* Bhh = dir ? bhh_r : bhh_f;

    s16x8 bfr[3][4];
    #pragma unroll
    for (int g = 0; g < 3; ++g) {
        const float* wrow = Whh + (size_t)(g * H_ + jcol) * H_;
        #pragma unroll
        for (int kt = 0; kt < 4; ++kt) {
            const float* p = wrow + kt * 32 + quad * 8;
            s16x8 f;
            #pragma unroll
            for (int i = 0; i < 8; ++i) f[i] = f2bs(p[i]);
            bfr[g][kt] = f;
        }
    }
    const float cnh = Bhh[2*H_ + jcol];
    const f32x4 sN = (f32x4){cnh, cnh, cnh, cnh};
    const f32x4 z4 = (f32x4){0.f, 0.f, 0.f, 0.f};

    for (int i = tid; i < 16 * HSTR; i += 512) hring[0][i] = __float2bfloat16(0.0f);
    if (tid == 0) syncnt = 0;

    const bf16* xgb = XG + (size_t)bg * T_ * G_ * 16;
    const size_t xo0 = ((size_t)0 * H_ + jcol) * 16 + quad * 4;
    const size_t xo1 = ((size_t)1 * H_ + jcol) * 16 + quad * 4;
    const size_t xo2 = ((size_t)2 * H_ + jcol) * 16 + quad * 4;

    uint2 xcur[WIN][3], xnxt[WIN][3];
    #pragma unroll
    for (int si = 0; si < WIN; ++si) {
        const int t = dir ? (T_ - 1 - si) : si;
        const size_t base = (size_t)t * G_ * 16;
        xcur[si][0] = *(const uint2*)(xgb + base + xo0);
        xcur[si][1] = *(const uint2*)(xgb + base + xo1);
        xcur[si][2] = *(const uint2*)(xgb + base + xo2);
    }
    __syncthreads();

    float hprev[4] = {0.f, 0.f, 0.f, 0.f};

    for (int w = 0; w < NW; ++w) {
        #pragma unroll
        for (int si = 0; si < WIN; ++si) {
            const int s  = w * WIN + si;
            const int rb = s & (RING - 1);
            const int wb = (s + 1) & (RING - 1);

            if (si == 0 && w + 1 < NW) {
                #pragma unroll
                for (int sj = 0; sj < WIN; ++sj) {
                    const int s2 = (w + 1) * WIN + sj;
                    const int t2 = dir ? (T_ - 1 - s2) : s2;
                    const size_t base = (size_t)t2 * G_ * 16;
                    xnxt[sj][0] = *(const uint2*)(xgb + base + xo0);
                    xnxt[sj][1] = *(const uint2*)(xgb + base + xo1);
                    xnxt[sj][2] = *(const uint2*)(xgb + base + xo2);
                }
            }

            // unpack xg -> accumulator seeds (register-only, overlaps sync/MFMA wait)
            const uint2 xr2 = xcur[si][0], xz2 = xcur[si][1], xn2 = xcur[si][2];
            const f32x4 seedR = (f32x4){
                __uint_as_float(xr2.x << 16), __uint_as_float(xr2.x & 0xffff0000u),
                __uint_as_float(xr2.y << 16), __uint_as_float(xr2.y & 0xffff0000u)};
            const f32x4 seedZ = (f32x4){
                __uint_as_float(xz2.x << 16), __uint_as_float(xz2.x & 0xffff0000u),
                __uint_as_float(xz2.y << 16), __uint_as_float(xz2.y & 0xffff0000u)};
            const float xnf[4] = {
                __uint_as_float(xn2.x << 16), __uint_as_float(xn2.x & 0xffff0000u),
                __uint_as_float(xn2.y << 16), __uint_as_float(xn2.y & 0xffff0000u)};

            s16x8 afr[4];
            #pragma unroll
            for (int kt = 0; kt < 4; ++kt)
                afr[kt] = *(const s16x8*)&hring[rb][col * HSTR + kt * 32 + quad * 8];

            f32x4 aR0 = MFMA16(afr[0], bfr[0][0], seedR);
            f32x4 aZ0 = MFMA16(afr[0], bfr[1][0], seedZ);
            f32x4 aN0 = MFMA16(afr[0], bfr[2][0], sN);
            f32x4 aR1 = MFMA16(afr[2], bfr[0][2], z4);
            f32x4 aZ1 = MFMA16(afr[2], bfr[1][2], z4);
            f32x4 aN1 = MFMA16(afr[2], bfr[2][2], z4);
            aR0 = MFMA16(afr[1], bfr[0][1], aR0);
            aZ0 = MFMA16(afr[1], bfr[1][1], aZ0);
            aN0 = MFMA16(afr[1], bfr[2][1], aN0);
            aR1 = MFMA16(afr[3], bfr[0][3], aR1);
            aZ1 = MFMA16(afr[3], bfr[1][3], aZ1);
            aN1 = MFMA16(afr[3], bfr[2][3], aN1);

            #pragma unroll
            for (int r = 0; r < 4; ++r) {
                const float rg = sigf(aR0[r] + aR1[r]);
                const float zg = sigf(aZ0[r] + aZ1[r]);
                const float ng = tanhf_(fmaf(rg, aN0[r] + aN1[r], xnf[r]));
                const float hn = fmaf(zg, hprev[r] - ng, ng);
                hprev[r] = hn;
                hring[wb][(quad * 4 + r) * HSTR + jcol] = __float2bfloat16(hn);
            }
            wave_sync(&syncnt, lane, (unsigned)(s + 1) * 8u);
        }

        // flush h history
        #pragma unroll
        for (int k = 0; k < 2; ++k) {
            const int c  = tid + k * 512;
            const int dt = c >> 8, m = (c >> 4) & 15, j8 = c & 15;
            const int s  = w * WIN + dt;
            const int t  = dir ? (T_ - 1 - s) : s;
            const uint4 v = *(const uint4*)&hring[(s + 1) & (RING - 1)][m * HSTR + j8 * 8];
            *(uint4*)(l1h + ((size_t)(b0 + m) * T_ + t) * 256 + dir * H_ + j8 * 8) = v;
        }
        #pragma unroll
        for (int si = 0; si < WIN; ++si) {
            xcur[si][0] = xnxt[si][0];
            xcur[si][1] = xnxt[si][1];
            xcur[si][2] = xnxt[si][2];
        }
    }
}

// ---------------------------------------------------------------------------
// FC epilogue: out[bt][c] = fc_b[c] + fc_w[c][:] . l1h[bt][:]
// ---------------------------------------------------------------------------
__global__ __launch_bounds__(256, 2) void fc_kernel(
    const bf16* __restrict__ h, const float* __restrict__ fcw,
    const float* __restrict__ fcb, float* __restrict__ out)
{
    __shared__ float w0[256], w1[256];
    const int tid = threadIdx.x;
    w0[tid] = fcw[tid];
    w1[tid] = fcw[256 + tid];
    __syncthreads();

    const size_t bt = (size_t)blockIdx.x * 256 + tid;
    const bf16* hp = h + bt * 256;
    float s0 = fcb[0], s1 = fcb[1];
    #pragma unroll 4
    for (int k8 = 0; k8 < 32; ++k8) {
        const uint4 u = *(const uint4*)(hp + k8 * 8);
        const unsigned uu[4] = {u.x, u.y, u.z, u.w};
        #pragma unroll
        for (int p = 0; p < 4; ++p) {
            const float v0 = __uint_as_float(uu[p] << 16);
            const float v1 = __uint_as_float(uu[p] & 0xffff0000u);
            const int k = k8 * 8 + p * 2;
            s0 = fmaf(w0[k], v0, s0);     s1 = fmaf(w1[k], v0, s1);
            s0 = fmaf(w0[k + 1], v1, s0); s1 = fmaf(w1[k + 1], v1, s1);
        }
    }
    out[bt * 2]     = s0;
    out[bt * 2 + 1] = s1;
}

extern "C" void kernel_launch(void* const* d_in, const int* in_sizes, int n_in,
                              void* d_out, int out_size, void* d_ws, size_t ws_size,
                              hipStream_t stream)
{
    if (n_in < 19) return;
    const float* x     = (const float*)d_in[0];
    const float* wih0  = (const float*)d_in[1];
    const float* whh0  = (const float*)d_in[2];
    const float* bih0  = (const float*)d_in[3];
    const float* bhh0  = (const float*)d_in[4];
    const float* wih0r = (const float*)d_in[5];
    const float* whh0r = (const float*)d_in[6];
    const float* bih0r = (const float*)d_in[7];
    const float* bhh0r = (const float*)d_in[8];
    const float* wih1  = (const float*)d_in[9];
    const float* whh1  = (const float*)d_in[10];
    const float* bih1  = (const float*)d_in[11];
    const float* bhh1  = (const float*)d_in[12];
    const float* wih1r = (const float*)d_in[13];
    const float* whh1r = (const float*)d_in[14];
    const float* bih1r = (const float*)d_in[15];
    const float* bhh1r = (const float*)d_in[16];
    const float* fcw   = (const float*)d_in[17];
    const float* fcb   = (const float*)d_in[18];
    float* out = (float*)d_out;

    const size_t nBT  = (size_t)B_ * T_;
    const size_t hh_b = nBT * 2 * H_ * sizeof(bf16);     // 64 MiB
    const size_t xg_b = nBT * G_ * sizeof(bf16);         // 96 MiB per dir
    const size_t xg_el = nBT * G_;

    if (ws_size >= hh_b + 2 * xg_b) {                    // 256 MiB path
        bf16* l0h = (bf16*)d_ws;
        bf16* xgf = (bf16*)((char*)d_ws + hh_b);
        bf16* xgr = xgf + xg_el;

        gru_l0_mfma<<<dim3(8), dim3(512), 0, stream>>>(
            x, wih0, whh0, bih0, bhh0, wih0r, whh0r, bih0r, bhh0r, l0h);
        xg_gemm_mfma<<<dim3(1024, 3, 2), dim3(256), 0, stream>>>(
            l0h, wih1, wih1r, bih1, bih1r, bhh1, bhh1r, xgf, xgr);
        gru_l1_mfma<<<dim3(8), dim3(512), 0, stream>>>(
            xgf, xgr, whh1, bhh1, whh1r, bhh1r, l0h, -1);   // l1h aliases l0h
        fc_kernel<<<dim3((int)(nBT / 256)), dim3(256), 0, stream>>>(l0h, fcw, fcb, out);
    } else if (ws_size >= 2 * hh_b + xg_b) {             // 224 MiB sequential
        bf16* l0h = (bf16*)d_ws;
        bf16* xg  = (bf16*)((char*)d_ws + hh_b);
        bf16* l1h = (bf16*)((char*)d_ws + hh_b + xg_b);

        gru_l0_mfma<<<dim3(8), dim3(512), 0, stream>>>(
            x, wih0, whh0, bih0, bhh0, wih0r, whh0r, bih0r, bhh0r, l0h);
        xg_gemm_mfma<<<dim3(1024, 3, 1), dim3(256), 0, stream>>>(
            l0h, wih1, wih1, bih1, bih1, bhh1, bhh1, xg, xg);
        gru_l1_mfma<<<dim3(4), dim3(512), 0, stream>>>(
            xg, xg, whh1, bhh1, whh1r, bhh1r, l1h, 0);
        xg_gemm_mfma<<<dim3(1024, 3, 1), dim3(256), 0, stream>>>(
            l0h, wih1r, wih1r, bih1r, bih1r, bhh1r, bhh1r, xg, xg);
        gru_l1_mfma<<<dim3(4), dim3(512), 0, stream>>>(
            xg, xg, whh1, bhh1, whh1r, bhh1r, l1h, 1);
        fc_kernel<<<dim3((int)(nBT / 256)), dim3(256), 0, stream>>>(l1h, fcw, fcb, out);
    }
}

// Round 13
// 3892.742 us; speedup vs baseline: 1.1773x; 1.0090x over previous
//
#include <hip/hip_runtime.h>
#include <hip/hip_bf16.h>

#define B_   64
#define T_   2048
#define H_   128
#define G_   384      // 3*H
#define D0_  18
#define WIN  4
#define RING 8
#define NW   (T_ / WIN)   // 512
#define HSTR 136          // h ring row stride in shorts

typedef __hip_bfloat16 bf16;
typedef __attribute__((ext_vector_type(4))) float f32x4;
typedef __attribute__((ext_vector_type(8))) short s16x8;

#define LOG2E 1.4426950408889634f
__device__ __forceinline__ float sigf(float x) {
    return __builtin_amdgcn_rcpf(1.0f + __builtin_amdgcn_exp2f(-LOG2E * x));
}
__device__ __forceinline__ float tanhf_(float x) {
    return 1.0f - 2.0f * __builtin_amdgcn_rcpf(1.0f + __builtin_amdgcn_exp2f((2.0f * LOG2E) * x));
}
__device__ __forceinline__ short f2bs(float v) {
    bf16 b = __float2bfloat16(v);
    return *reinterpret_cast<short*>(&b);
}
#define MFMA16(A, B, C) __builtin_amdgcn_mfma_f32_16x16x32_bf16((A), (B), (C), 0, 0, 0)

// WG-level wave sync, fence-free: DS ops from one wave execute in order, so
// the counter bump issued after our h'-writes implies their visibility.
// Compiler barrier only (no s_waitcnt lgkmcnt(0) on the writer path).
__device__ __forceinline__ void wave_sync(unsigned* cnt, int lane, unsigned tgt) {
    __asm__ volatile("" ::: "memory");
    if (lane == 0)
        __hip_atomic_fetch_add(cnt, 1u, __ATOMIC_RELAXED, __HIP_MEMORY_SCOPE_WORKGROUP);
    while (__hip_atomic_load(cnt, __ATOMIC_RELAXED, __HIP_MEMORY_SCOPE_WORKGROUP) < tgt) {}
    __asm__ volatile("" ::: "memory");
}

// ---------------------------------------------------------------------------
// Layer 0 scan: fused x-projection, accumulator-seeded biases.
// 8 WGs (dir = bx>>2, 16 batches each) x 512 thr (8 waves).
// Post-sync issue order: A-frag ds_reads -> x-MFMAs (latency fill) ->
// h-MFMAs -> prefetch burst (in MFMA shadow) -> gates -> write -> sync.
// ---------------------------------------------------------------------------
__global__ __launch_bounds__(512) void gru_l0_mfma(
    const float* __restrict__ x,
    const float* __restrict__ wih_f, const float* __restrict__ whh_f,
    const float* __restrict__ bih_f, const float* __restrict__ bhh_f,
    const float* __restrict__ wih_r, const float* __restrict__ whh_r,
    const float* __restrict__ bih_r, const float* __restrict__ bhh_r,
    bf16* __restrict__ l0h)
{
    __shared__ __align__(16) bf16 hring[RING][16 * HSTR];
    __shared__ __align__(16) bf16 xbuf[2][WIN][16][40];
    __shared__ unsigned syncnt;

    const int bx   = blockIdx.x;
    const int dir  = bx >> 2;
    const int bg   = bx & 3;
    const int b0   = bg * 16;
    const int tid  = threadIdx.x;
    const int lane = tid & 63;
    const int wv   = tid >> 6;
    const int col  = lane & 15;
    const int quad = lane >> 4;
    const int jcol = wv * 16 + col;

    const float* Wih = dir ? wih_r : wih_f;
    const float* Whh = dir ? whh_r : whh_f;
    const float* Bih = dir ? bih_r : bih_f;
    const float* Bhh = dir ? bhh_r : bhh_f;

    s16x8 bfr[3][4], bxf[3];
    #pragma unroll
    for (int g = 0; g < 3; ++g) {
        const float* wrow = Whh + (size_t)(g * H_ + jcol) * H_;
        #pragma unroll
        for (int kt = 0; kt < 4; ++kt) {
            const float* p = wrow + kt * 32 + quad * 8;
            s16x8 f;
            #pragma unroll
            for (int i = 0; i < 8; ++i) f[i] = f2bs(p[i]);
            bfr[g][kt] = f;
        }
        const float* xrow = Wih + (size_t)(g * H_ + jcol) * D0_;
        s16x8 fx;
        #pragma unroll
        for (int i = 0; i < 8; ++i) {
            const int k = quad * 8 + i;
            fx[i] = (k < D0_) ? f2bs(xrow[k]) : (short)0;
        }
        bxf[g] = fx;
    }
    const float crz0 = Bih[jcol]        + Bhh[jcol];
    const float crz1 = Bih[H_ + jcol]   + Bhh[H_ + jcol];
    const float bnx  = Bih[2*H_ + jcol];
    const float bnh  = Bhh[2*H_ + jcol];
    const f32x4 sR = (f32x4){crz0, crz0, crz0, crz0};
    const f32x4 sZ = (f32x4){crz1, crz1, crz1, crz1};
    const f32x4 sX = (f32x4){bnx, bnx, bnx, bnx};
    const f32x4 sN = (f32x4){bnh, bnh, bnh, bnh};
    const f32x4 z4 = (f32x4){0.f, 0.f, 0.f, 0.f};

    for (int i = tid; i < 16 * HSTR; i += 512) hring[0][i] = __float2bfloat16(0.0f);
    if (tid == 0) syncnt = 0;
    #pragma unroll
    for (int k = 0; k < 4; ++k) {
        const int i = tid + k * 512;
        const int si = i >> 9, m = (i >> 5) & 15, c = i & 31;
        const int t = dir ? (T_ - 1 - si) : si;
        const float v = (c < D0_) ? x[((size_t)(b0 + m) * T_ + t) * D0_ + c] : 0.0f;
        xbuf[0][si][m][c] = __float2bfloat16(v);
    }
    __syncthreads();

    float hprev[4] = {0.f, 0.f, 0.f, 0.f};
    float xv[4];

    for (int w = 0; w < NW; ++w) {
        const int par = w & 1;
        s16x8 axf[WIN];
        #pragma unroll
        for (int si = 0; si < WIN; ++si)
            axf[si] = *(const s16x8*)&xbuf[par][si][col][quad * 8];

        #pragma unroll
        for (int si = 0; si < WIN; ++si) {
            const int s  = w * WIN + si;
            const int rb = s & (RING - 1);
            const int wb = (s + 1) & (RING - 1);

            // A-frag reads first (long pole)
            s16x8 afr[4];
            #pragma unroll
            for (int kt = 0; kt < 4; ++kt)
                afr[kt] = *(const s16x8*)&hring[rb][col * HSTR + kt * 32 + quad * 8];

            // x-MFMAs fill the ds_read latency (no dependency on afr)
            f32x4 aR1 = MFMA16(axf[si], bxf[0], z4);
            f32x4 aZ1 = MFMA16(axf[si], bxf[1], z4);
            f32x4 aX  = MFMA16(axf[si], bxf[2], sX);

            f32x4 aR0 = MFMA16(afr[0], bfr[0][0], sR);
            f32x4 aZ0 = MFMA16(afr[0], bfr[1][0], sZ);
            f32x4 aN0 = MFMA16(afr[0], bfr[2][0], sN);
            aR1 = MFMA16(afr[2], bfr[0][2], aR1);
            aZ1 = MFMA16(afr[2], bfr[1][2], aZ1);
            f32x4 aN1 = MFMA16(afr[2], bfr[2][2], z4);
            aR0 = MFMA16(afr[1], bfr[0][1], aR0);
            aZ0 = MFMA16(afr[1], bfr[1][1], aZ0);
            aN0 = MFMA16(afr[1], bfr[2][1], aN0);
            aR1 = MFMA16(afr[3], bfr[0][3], aR1);
            aZ1 = MFMA16(afr[3], bfr[1][3], aZ1);
            aN1 = MFMA16(afr[3], bfr[2][3], aN1);

            // prefetch burst in the MFMA latency shadow (consumed at si==3)
            if (si == 0 && w + 1 < NW) {
                #pragma unroll
                for (int k = 0; k < 4; ++k) {
                    const int i = tid + k * 512;
                    const int sj = i >> 9, m = (i >> 5) & 15, c = i & 31;
                    const int s2 = (w + 1) * WIN + sj;
                    const int t2 = dir ? (T_ - 1 - s2) : s2;
                    xv[k] = (c < D0_) ? x[((size_t)(b0 + m) * T_ + t2) * D0_ + c] : 0.0f;
                }
            }

            #pragma unroll
            for (int r = 0; r < 4; ++r) {
                const float rg = sigf(aR0[r] + aR1[r]);
                const float zg = sigf(aZ0[r] + aZ1[r]);
                const float ng = tanhf_(fmaf(rg, aN0[r] + aN1[r], aX[r]));
                const float hn = fmaf(zg, hprev[r] - ng, ng);
                hprev[r] = hn;
                hring[wb][(quad * 4 + r) * HSTR + jcol] = __float2bfloat16(hn);
            }

            if (si == 3 && w + 1 < NW) {
                #pragma unroll
                for (int k = 0; k < 4; ++k) {
                    const int i = tid + k * 512;
                    const int sj = i >> 9, m = (i >> 5) & 15, c = i & 31;
                    xbuf[par ^ 1][sj][m][c] = __float2bfloat16(xv[k]);
                }
            }
            wave_sync(&syncnt, lane, (unsigned)(s + 1) * 8u);
        }

        // flush h history (fire-and-forget stores, never force-drained)
        #pragma unroll
        for (int k = 0; k < 2; ++k) {
            const int c  = tid + k * 512;
            const int dt = c >> 8, m = (c >> 4) & 15, j8 = c & 15;
            const int s  = w * WIN + dt;
            const int t  = dir ? (T_ - 1 - s) : s;
            const uint4 v = *(const uint4*)&hring[(s + 1) & (RING - 1)][m * HSTR + j8 * 8];
            *(uint4*)(l0h + ((size_t)(b0 + m) * T_ + t) * 256 + dir * H_ + j8 * 8) = v;
        }
    }
}

// ---------------------------------------------------------------------------
// xg GEMM (both dirs, grid.z): C = l0h(131072x256 bf16) . W^T + bias, where
// bias = bih[n] + (n<256 ? bhh[n] : 0)  -- r,z biases folded in.
// Output layout xg[((bg*T+t)*G + n)*16 + (b&15)] bf16.
// ---------------------------------------------------------------------------
__global__ __launch_bounds__(256, 2) void xg_gemm_mfma(
    const bf16* __restrict__ A,
    const float* __restrict__ w_f, const float* __restrict__ w_r,
    const float* __restrict__ bi_f, const float* __restrict__ bi_r,
    const float* __restrict__ bh_f, const float* __restrict__ bh_r,
    bf16* __restrict__ xg_f, bf16* __restrict__ xg_r)
{
    __shared__ short As[128 * 40];
    __shared__ short Ws[128 * 40];
    __shared__ float Bias_s[128];

    const int dir  = blockIdx.z;
    const float* W   = dir ? w_r : w_f;
    const float* bi  = dir ? bi_r : bi_f;
    const float* bh  = dir ? bh_r : bh_f;
    bf16* xg         = dir ? xg_r : xg_f;

    const int tid  = threadIdx.x;
    const int lane = tid & 63;
    const int wv   = tid >> 6;
    const int m0   = blockIdx.x * 128;
    const int n0   = blockIdx.y * 128;

    if (tid < 128) {
        const int n = n0 + tid;
        Bias_s[tid] = bi[n] + ((n < 2 * H_) ? bh[n] : 0.0f);
    }

    f32x4 acc[2][8];
    #pragma unroll
    for (int mt = 0; mt < 2; ++mt)
        #pragma unroll
        for (int nt = 0; nt < 8; ++nt) acc[mt][nt] = (f32x4){0.f, 0.f, 0.f, 0.f};

    for (int k0 = 0; k0 < 256; k0 += 32) {
        #pragma unroll
        for (int i = 0; i < 2; ++i) {
            const int c = tid + i * 256;
            const int row = c >> 2, quad = c & 3;
            *(uint4*)&As[row * 40 + quad * 8] =
                *(const uint4*)(A + (size_t)(m0 + row) * 256 + k0 + quad * 8);
        }
        #pragma unroll
        for (int i = 0; i < 4; ++i) {
            const int c = tid + i * 256;
            const int row = c >> 3, q = c & 7;
            const float4 v = *(const float4*)(W + (size_t)(n0 + row) * 256 + k0 + q * 4);
            ushort4 u;
            u.x = (unsigned short)f2bs(v.x); u.y = (unsigned short)f2bs(v.y);
            u.z = (unsigned short)f2bs(v.z); u.w = (unsigned short)f2bs(v.w);
            *(ushort4*)&Ws[row * 40 + q * 4] = u;
        }
        __syncthreads();

        s16x8 afr[2], bfr[8];
        #pragma unroll
        for (int mt = 0; mt < 2; ++mt)
            afr[mt] = *(const s16x8*)&As[(wv * 32 + mt * 16 + (lane & 15)) * 40 + (lane >> 4) * 8];
        #pragma unroll
        for (int nt = 0; nt < 8; ++nt)
            bfr[nt] = *(const s16x8*)&Ws[(nt * 16 + (lane & 15)) * 40 + (lane >> 4) * 8];

        #pragma unroll
        for (int mt = 0; mt < 2; ++mt)
            #pragma unroll
            for (int nt = 0; nt < 8; ++nt)
                acc[mt][nt] = MFMA16(afr[mt], bfr[nt], acc[mt][nt]);
        __syncthreads();
    }

    #pragma unroll
    for (int mt = 0; mt < 2; ++mt) {
        #pragma unroll
        for (int nt = 0; nt < 8; ++nt) {
            const int n_g = n0 + nt * 16 + (lane & 15);
            const float bv = Bias_s[nt * 16 + (lane & 15)];
            #pragma unroll
            for (int r = 0; r < 4; ++r) {
                const int m_g = m0 + wv * 32 + mt * 16 + (lane >> 4) * 4 + r;
                const int b = m_g >> 11, t = m_g & 2047;
                const size_t off = (((size_t)(b >> 4) * T_ + t) * G_ + n_g) * 16 + (b & 15);
                xg[off] = __float2bfloat16(acc[mt][nt][r] + bv);
            }
        }
    }
}

// ---------------------------------------------------------------------------
// Layer 1 scan: xg register-prefetched; accumulators seeded with unpacked xg
// (r,z incl. all biases) and bhh_n. Post-sync order: A-frag reads -> seed
// unpack (latency fill) -> MFMAs -> prefetch burst (MFMA shadow) -> gates.
// ---------------------------------------------------------------------------
__global__ __launch_bounds__(512) void gru_l1_mfma(
    const bf16* __restrict__ xg_f, const bf16* __restrict__ xg_r,
    const float* __restrict__ whh_f, const float* __restrict__ bhh_f,
    const float* __restrict__ whh_r, const float* __restrict__ bhh_r,
    bf16* __restrict__ l1h, int fixed_dir)
{
    __shared__ __align__(16) bf16 hring[RING][16 * HSTR];
    __shared__ unsigned syncnt;

    const int bx   = blockIdx.x;
    const int dir  = (fixed_dir >= 0) ? fixed_dir : (bx >> 2);
    const int bg   = bx & 3;
    const int b0   = bg * 16;
    const int tid  = threadIdx.x;
    const int lane = tid & 63;
    const int wv   = tid >> 6;
    const int col  = lane & 15;
    const int quad = lane >> 4;
    const int jcol = wv * 16 + col;

    const bf16*  XG  = dir ? xg_r : xg_f;
    const float* Whh = dir ? whh_r : whh_f;
    const float* Bhh = dir ? bhh_r : bhh_f;

    s16x8 bfr[3][4];
    #pragma unroll
    for (int g = 0; g < 3; ++g) {
        const float* wrow = Whh + (size_t)(g * H_ + jcol) * H_;
        #pragma unroll
        for (int kt = 0; kt < 4; ++kt) {
            const float* p = wrow + kt * 32 + quad * 8;
            s16x8 f;
            #pragma unroll
            for (int i = 0; i < 8; ++i) f[i] = f2bs(p[i]);
            bfr[g][kt] = f;
        }
    }
    const float cnh = Bhh[2*H_ + jcol];
    const f32x4 sN = (f32x4){cnh, cnh, cnh, cnh};
    const f32x4 z4 = (f32x4){0.f, 0.f, 0.f, 0.f};

    for (int i = tid; i < 16 * HSTR; i += 512) hring[0][i] = __float2bfloat16(0.0f);
    if (tid == 0) syncnt = 0;

    const bf16* xgb = XG + (size_t)bg * T_ * G_ * 16;
    const size_t xo0 = ((size_t)0 * H_ + jcol) * 16 + quad * 4;
    const size_t xo1 = ((size_t)1 * H_ + jcol) * 16 + quad * 4;
    const size_t xo2 = ((size_t)2 * H_ + jcol) * 16 + quad * 4;

    uint2 xcur[WIN][3], xnxt[WIN][3];
    #pragma unroll
    for (int si = 0; si < WIN; ++si) {
        const int t = dir ? (T_ - 1 - si) : si;
        const size_t base = (size_t)t * G_ * 16;
        xcur[si][0] = *(const uint2*)(xgb + base + xo0);
        xcur[si][1] = *(const uint2*)(xgb + base + xo1);
        xcur[si][2] = *(const uint2*)(xgb + base + xo2);
    }
    __syncthreads();

    float hprev[4] = {0.f, 0.f, 0.f, 0.f};

    for (int w = 0; w < NW; ++w) {
        #pragma unroll
        for (int si = 0; si < WIN; ++si) {
            const int s  = w * WIN + si;
            const int rb = s & (RING - 1);
            const int wb = (s + 1) & (RING - 1);

            // A-frag reads first (long pole after sync)
            s16x8 afr[4];
            #pragma unroll
            for (int kt = 0; kt < 4; ++kt)
                afr[kt] = *(const s16x8*)&hring[rb][col * HSTR + kt * 32 + quad * 8];

            // seed unpack fills the ds_read latency (register-only)
            const uint2 xr2 = xcur[si][0], xz2 = xcur[si][1], xn2 = xcur[si][2];
            const f32x4 seedR = (f32x4){
                __uint_as_float(xr2.x << 16), __uint_as_float(xr2.x & 0xffff0000u),
                __uint_as_float(xr2.y << 16), __uint_as_float(xr2.y & 0xffff0000u)};
            const f32x4 seedZ = (f32x4){
                __uint_as_float(xz2.x << 16), __uint_as_float(xz2.x & 0xffff0000u),
                __uint_as_float(xz2.y << 16), __uint_as_float(xz2.y & 0xffff0000u)};
            const float xnf[4] = {
                __uint_as_float(xn2.x << 16), __uint_as_float(xn2.x & 0xffff0000u),
                __uint_as_float(xn2.y << 16), __uint_as_float(xn2.y & 0xffff0000u)};

            f32x4 aR0 = MFMA16(afr[0], bfr[0][0], seedR);
            f32x4 aZ0 = MFMA16(afr[0], bfr[1][0], seedZ);
            f32x4 aN0 = MFMA16(afr[0], bfr[2][0], sN);
            f32x4 aR1 = MFMA16(afr[2], bfr[0][2], z4);
            f32x4 aZ1 = MFMA16(afr[2], bfr[1][2], z4);
            f32x4 aN1 = MFMA16(afr[2], bfr[2][2], z4);
            aR0 = MFMA16(afr[1], bfr[0][1], aR0);
            aZ0 = MFMA16(afr[1], bfr[1][1], aZ0);
            aN0 = MFMA16(afr[1], bfr[2][1], aN0);
            aR1 = MFMA16(afr[3], bfr[0][3], aR1);
            aZ1 = MFMA16(afr[3], bfr[1][3], aZ1);
            aN1 = MFMA16(afr[3], bfr[2][3], aN1);

            // prefetch burst in the MFMA latency shadow (off the sync chain)
            if (si == 0 && w + 1 < NW) {
                #pragma unroll
                for (int sj = 0; sj < WIN; ++sj) {
                    const int s2 = (w + 1) * WIN + sj;
                    const int t2 = dir ? (T_ - 1 - s2) : s2;
                    const size_t base = (size_t)t2 * G_ * 16;
                    xnxt[sj][0] = *(const uint2*)(xgb + base + xo0);
                    xnxt[sj][1] = *(const uint2*)(xgb + base + xo1);
                    xnxt[sj][2] = *(const uint2*)(xgb + base + xo2);
                }
            }

            #pragma unroll
            for (int r = 0; r < 4; ++r) {
                const float rg = sigf(aR0[r] + aR1[r]);
                const float zg = sigf(aZ0[r] + aZ1[r]);
                const float ng = tanhf_(fmaf(rg, aN0[r] + aN1[r], xnf[r]));
                const float hn = fmaf(zg, hprev[r] - ng, ng);
                hprev[r] = hn;
                hring[wb][(quad * 4 + r) * HSTR + jcol] = __float2bfloat16(hn);
            }
            wave_sync(&syncnt, lane, (unsigned)(s + 1) * 8u);
        }

        // flush h history
        #pragma unroll
        for (int k = 0; k < 2; ++k) {
            const int c  = tid + k * 512;
            const int dt = c >> 8, m = (c >> 4) & 15, j8 = c & 15;
            const int s  = w * WIN + dt;
            const int t  = dir ? (T_ - 1 - s) : s;
            const uint4 v = *(const uint4*)&hring[(s + 1) & (RING - 1)][m * HSTR + j8 * 8];
            *(uint4*)(l1h + ((size_t)(b0 + m) * T_ + t) * 256 + dir * H_ + j8 * 8) = v;
        }
        #pragma unroll
        for (int si = 0; si < WIN; ++si) {
            xcur[si][0] = xnxt[si][0];
            xcur[si][1] = xnxt[si][1];
            xcur[si][2] = xnxt[si][2];
        }
    }
}

// ---------------------------------------------------------------------------
// FC epilogue: out[bt][c] = fc_b[c] + fc_w[c][:] . l1h[bt][:]
// ---------------------------------------------------------------------------
__global__ __launch_bounds__(256, 2) void fc_kernel(
    const bf16* __restrict__ h, const float* __restrict__ fcw,
    const float* __restrict__ fcb, float* __restrict__ out)
{
    __shared__ float w0[256], w1[256];
    const int tid = threadIdx.x;
    w0[tid] = fcw[tid];
    w1[tid] = fcw[256 + tid];
    __syncthreads();

    const size_t bt = (size_t)blockIdx.x * 256 + tid;
    const bf16* hp = h + bt * 256;
    float s0 = fcb[0], s1 = fcb[1];
    #pragma unroll 4
    for (int k8 = 0; k8 < 32; ++k8) {
        const uint4 u = *(const uint4*)(hp + k8 * 8);
        const unsigned uu[4] = {u.x, u.y, u.z, u.w};
        #pragma unroll
        for (int p = 0; p < 4; ++p) {
            const float v0 = __uint_as_float(uu[p] << 16);
            const float v1 = __uint_as_float(uu[p] & 0xffff0000u);
            const int k = k8 * 8 + p * 2;
            s0 = fmaf(w0[k], v0, s0);     s1 = fmaf(w1[k], v0, s1);
            s0 = fmaf(w0[k + 1], v1, s0); s1 = fmaf(w1[k + 1], v1, s1);
        }
    }
    out[bt * 2]     = s0;
    out[bt * 2 + 1] = s1;
}

extern "C" void kernel_launch(void* const* d_in, const int* in_sizes, int n_in,
                              void* d_out, int out_size, void* d_ws, size_t ws_size,
                              hipStream_t stream)
{
    if (n_in < 19) return;
    const float* x     = (const float*)d_in[0];
    const float* wih0  = (const float*)d_in[1];
    const float* whh0  = (const float*)d_in[2];
    const float* bih0  = (const float*)d_in[3];
    const float* bhh0  = (const float*)d_in[4];
    const float* wih0r = (const float*)d_in[5];
    const float* whh0r = (const float*)d_in[6];
    const float* bih0r = (const float*)d_in[7];
    const float* bhh0r = (const float*)d_in[8];
    const float* wih1  = (const float*)d_in[9];
    const float* whh1  = (const float*)d_in[10];
    const float* bih1  = (const float*)d_in[11];
    const float* bhh1  = (const float*)d_in[12];
    const float* wih1r = (const float*)d_in[13];
    const float* whh1r = (const float*)d_in[14];
    const float* bih1r = (const float*)d_in[15];
    const float* bhh1r = (const float*)d_in[16];
    const float* fcw   = (const float*)d_in[17];
    const float* fcb   = (const float*)d_in[18];
    float* out = (float*)d_out;

    const size_t nBT  = (size_t)B_ * T_;
    const size_t hh_b = nBT * 2 * H_ * sizeof(bf16);     // 64 MiB
    const size_t xg_b = nBT * G_ * sizeof(bf16);         // 96 MiB per dir
    const size_t xg_el = nBT * G_;

    if (ws_size >= hh_b + 2 * xg_b) {                    // 256 MiB path
        bf16* l0h = (bf16*)d_ws;
        bf16* xgf = (bf16*)((char*)d_ws + hh_b);
        bf16* xgr = xgf + xg_el;

        gru_l0_mfma<<<dim3(8), dim3(512), 0, stream>>>(
            x, wih0, whh0, bih0, bhh0, wih0r, whh0r, bih0r, bhh0r, l0h);
        xg_gemm_mfma<<<dim3(1024, 3, 2), dim3(256), 0, stream>>>(
            l0h, wih1, wih1r, bih1, bih1r, bhh1, bhh1r, xgf, xgr);
        gru_l1_mfma<<<dim3(8), dim3(512), 0, stream>>>(
            xgf, xgr, whh1, bhh1, whh1r, bhh1r, l0h, -1);   // l1h aliases l0h
        fc_kernel<<<dim3((int)(nBT / 256)), dim3(256), 0, stream>>>(l0h, fcw, fcb, out);
    } else if (ws_size >= 2 * hh_b + xg_b) {             // 224 MiB sequential
        bf16* l0h = (bf16*)d_ws;
        bf16* xg  = (bf16*)((char*)d_ws + hh_b);
        bf16* l1h = (bf16*)((char*)d_ws + hh_b + xg_b);

        gru_l0_mfma<<<dim3(8), dim3(512), 0, stream>>>(
            x, wih0, whh0, bih0, bhh0, wih0r, whh0r, bih0r, bhh0r, l0h);
        xg_gemm_mfma<<<dim3(1024, 3, 1), dim3(256), 0, stream>>>(
            l0h, wih1, wih1, bih1, bih1, bhh1, bhh1, xg, xg);
        gru_l1_mfma<<<dim3(4), dim3(512), 0, stream>>>(
            xg, xg, whh1, bhh1, whh1r, bhh1r, l1h, 0);
        xg_gemm_mfma<<<dim3(1024, 3, 1), dim3(256), 0, stream>>>(
            l0h, wih1r, wih1r, bih1r, bih1r, bhh1r, bhh1r, xg, xg);
        gru_l1_mfma<<<dim3(4), dim3(512), 0, stream>>>(
            xg, xg, whh1, bhh1, whh1r, bhh1r, l1h, 1);
        fc_kernel<<<dim3((int)(nBT / 256)), dim3(256), 0, stream>>>(l1h, fcw, fcb, out);
    }
}

// Round 14
// 3708.542 us; speedup vs baseline: 1.2358x; 1.0497x over previous
//
#include <hip/hip_runtime.h>
#include <hip/hip_bf16.h>

#define B_   64
#define T_   2048
#define H_   128
#define G_   384      // 3*H
#define D0_  18
#define WIN  4
#define RING 8
#define NW   (T_ / WIN)   // 512

typedef __hip_bfloat16 bf16;
typedef __attribute__((ext_vector_type(4))) float f32x4;
typedef __attribute__((ext_vector_type(8))) short s16x8;

#define LOG2E 1.4426950408889634f
__device__ __forceinline__ float sigf(float x) {
    return __builtin_amdgcn_rcpf(1.0f + __builtin_amdgcn_exp2f(-LOG2E * x));
}
__device__ __forceinline__ float tanhf_(float x) {
    return 1.0f - 2.0f * __builtin_amdgcn_rcpf(1.0f + __builtin_amdgcn_exp2f((2.0f * LOG2E) * x));
}
__device__ __forceinline__ short f2bs(float v) {
    bf16 b = __float2bfloat16(v);
    return *reinterpret_cast<short*>(&b);
}
__device__ __forceinline__ unsigned short f2bu(float v) {
    bf16 b = __float2bfloat16(v);
    return *reinterpret_cast<unsigned short*>(&b);
}
#define MFMA16(A, B, C) __builtin_amdgcn_mfma_f32_16x16x32_bf16((A), (B), (C), 0, 0, 0)

// Fence-free WG wave sync (validated R13: DS ops in wave order).
__device__ __forceinline__ void wave_sync(unsigned* cnt, int lane, unsigned tgt) {
    __asm__ volatile("" ::: "memory");
    if (lane == 0)
        __hip_atomic_fetch_add(cnt, 1u, __ATOMIC_RELAXED, __HIP_MEMORY_SCOPE_WORKGROUP);
    while (__hip_atomic_load(cnt, __ATOMIC_RELAXED, __HIP_MEMORY_SCOPE_WORKGROUP) < tgt) {}
    __asm__ volatile("" ::: "memory");
}

// h ring slot: B-frag order. flat short idx = kt*512 + l*8 + i holds
// h[k = kt*32 + (l>>4)*8 + i][batch = l&15]. Reads: ds_read_b128 at lane*16B
// (conflict-free canonical). Writes: one ds_write_b64 per lane (4-way).
// Slot = 2048 shorts (4 KiB); 8 slots = 32 KiB.

// ---------------------------------------------------------------------------
// Layer 0 scan: gates D[j][m] = Whh_A . h_B (+ Wih_A . x_B). 8 WGs x 512 thr.
// ---------------------------------------------------------------------------
__global__ __launch_bounds__(512) void gru_l0_mfma(
    const float* __restrict__ x,
    const float* __restrict__ wih_f, const float* __restrict__ whh_f,
    const float* __restrict__ bih_f, const float* __restrict__ bhh_f,
    const float* __restrict__ wih_r, const float* __restrict__ whh_r,
    const float* __restrict__ bih_r, const float* __restrict__ bhh_r,
    bf16* __restrict__ l0h)
{
    __shared__ __align__(16) bf16 hring[RING][2048];
    __shared__ __align__(16) bf16 xbuf[2][WIN][512];   // B-frag order, k<32 pad
    __shared__ unsigned syncnt;

    const int bx   = blockIdx.x;
    const int dir  = bx >> 2;
    const int bg   = bx & 3;
    const int b0   = bg * 16;
    const int tid  = threadIdx.x;
    const int lane = tid & 63;
    const int wv   = tid >> 6;       // = jt (j-tile)
    const int col  = lane & 15;
    const int quad = lane >> 4;

    const float* Wih = dir ? wih_r : wih_f;
    const float* Whh = dir ? whh_r : whh_f;
    const float* Bih = dir ? bih_r : bih_f;
    const float* Bhh = dir ? bhh_r : bhh_f;

    // A-frags: lane holds W[row = tile + col][k = kt*32 + quad*8 + i]
    s16x8 wfr[3][4], wxf[3];
    #pragma unroll
    for (int g = 0; g < 3; ++g) {
        const float* wrow = Whh + (size_t)(g * H_ + wv * 16 + col) * H_;
        #pragma unroll
        for (int kt = 0; kt < 4; ++kt) {
            const float* p = wrow + kt * 32 + quad * 8;
            s16x8 f;
            #pragma unroll
            for (int i = 0; i < 8; ++i) f[i] = f2bs(p[i]);
            wfr[g][kt] = f;
        }
        const float* xrow = Wih + (size_t)(g * H_ + wv * 16 + col) * D0_;
        s16x8 fx;
        #pragma unroll
        for (int i = 0; i < 8; ++i) {
            const int k = quad * 8 + i;
            fx[i] = (k < D0_) ? f2bs(xrow[k]) : (short)0;
        }
        wxf[g] = fx;
    }
    // per-r seeds: j = wv*16 + quad*4 + r
    f32x4 sR, sZ, sX, sN;
    #pragma unroll
    for (int r = 0; r < 4; ++r) {
        const int j = wv * 16 + quad * 4 + r;
        sR[r] = Bih[j]        + Bhh[j];
        sZ[r] = Bih[H_ + j]   + Bhh[H_ + j];
        sX[r] = Bih[2*H_ + j];
        sN[r] = Bhh[2*H_ + j];
    }
    const f32x4 z4 = (f32x4){0.f, 0.f, 0.f, 0.f};

    // h' write slot (B-frag position for j = wv*16+quad*4+r, m = col)
    const int wkt   = wv >> 1;
    const int wl    = (((wv << 1) + (quad >> 1)) & 3) * 16 + col;
    const int woff  = wkt * 512 + wl * 8 + (quad & 1) * 4;   // shorts

    for (int i = tid; i < 2048; i += 512) hring[0][i] = __float2bfloat16(0.0f);
    if (tid == 0) syncnt = 0;
    // stage x window 0 (B-frag order)
    #pragma unroll
    for (int k = 0; k < 4; ++k) {
        const int i = tid + k * 512;
        const int si = i >> 9, rem = i & 511;
        const int m = (rem >> 5) & 15, c = rem & 31;
        const int t = dir ? (T_ - 1 - si) : si;
        const float v = (c < D0_) ? x[((size_t)(b0 + m) * T_ + t) * D0_ + c] : 0.0f;
        xbuf[0][si][((c >> 3) * 16 + m) * 8 + (c & 7)] = __float2bfloat16(v);
    }
    __syncthreads();

    float hprev[4] = {0.f, 0.f, 0.f, 0.f};
    float xv[4];

    for (int w = 0; w < NW; ++w) {
        const int par = w & 1;
        s16x8 axf[WIN];
        #pragma unroll
        for (int si = 0; si < WIN; ++si)
            axf[si] = *(const s16x8*)&xbuf[par][si][lane * 8];

        #pragma unroll
        for (int si = 0; si < WIN; ++si) {
            const int s  = w * WIN + si;
            const int rb = s & (RING - 1);
            const int wb = (s + 1) & (RING - 1);

            // B-frag h reads: contiguous lane*16B per kt block (conflict-free)
            s16x8 hfr[4];
            #pragma unroll
            for (int kt = 0; kt < 4; ++kt)
                hfr[kt] = *(const s16x8*)&hring[rb][kt * 512 + lane * 8];

            // x-MFMAs fill the ds_read latency
            f32x4 aR1 = MFMA16(wxf[0], axf[si], z4);
            f32x4 aZ1 = MFMA16(wxf[1], axf[si], z4);
            f32x4 aX  = MFMA16(wxf[2], axf[si], sX);

            f32x4 aR0 = MFMA16(wfr[0][0], hfr[0], sR);
            f32x4 aZ0 = MFMA16(wfr[1][0], hfr[0], sZ);
            f32x4 aN0 = MFMA16(wfr[2][0], hfr[0], sN);
            aR1 = MFMA16(wfr[0][2], hfr[2], aR1);
            aZ1 = MFMA16(wfr[1][2], hfr[2], aZ1);
            f32x4 aN1 = MFMA16(wfr[2][2], hfr[2], z4);
            aR0 = MFMA16(wfr[0][1], hfr[1], aR0);
            aZ0 = MFMA16(wfr[1][1], hfr[1], aZ0);
            aN0 = MFMA16(wfr[2][1], hfr[1], aN0);
            aR1 = MFMA16(wfr[0][3], hfr[3], aR1);
            aZ1 = MFMA16(wfr[1][3], hfr[3], aZ1);
            aN1 = MFMA16(wfr[2][3], hfr[3], aN1);

            // prefetch next window's x in the MFMA shadow
            if (si == 0 && w + 1 < NW) {
                #pragma unroll
                for (int k = 0; k < 4; ++k) {
                    const int i = tid + k * 512;
                    const int sj = i >> 9, rem = i & 511;
                    const int m = (rem >> 5) & 15, c = rem & 31;
                    const int s2 = (w + 1) * WIN + sj;
                    const int t2 = dir ? (T_ - 1 - s2) : s2;
                    xv[k] = (c < D0_) ? x[((size_t)(b0 + m) * T_ + t2) * D0_ + c] : 0.0f;
                }
            }

            unsigned short hb[4];
            #pragma unroll
            for (int r = 0; r < 4; ++r) {
                const float rg = sigf(aR0[r] + aR1[r]);
                const float zg = sigf(aZ0[r] + aZ1[r]);
                const float ng = tanhf_(fmaf(rg, aN0[r] + aN1[r], aX[r]));
                const float hn = fmaf(zg, hprev[r] - ng, ng);
                hprev[r] = hn;
                hb[r] = f2bu(hn);
            }
            // single b64 store of 4 consecutive bf16
            uint2 wv2;
            wv2.x = (unsigned)hb[0] | ((unsigned)hb[1] << 16);
            wv2.y = (unsigned)hb[2] | ((unsigned)hb[3] << 16);
            *(uint2*)&hring[wb][woff] = wv2;

            if (si == 3 && w + 1 < NW) {
                #pragma unroll
                for (int k = 0; k < 4; ++k) {
                    const int i = tid + k * 512;
                    const int sj = i >> 9, rem = i & 511;
                    const int m = (rem >> 5) & 15, c = rem & 31;
                    xbuf[par ^ 1][sj][((c >> 3) * 16 + m) * 8 + (c & 7)] =
                        __float2bfloat16(xv[k]);
                }
            }
            wave_sync(&syncnt, lane, (unsigned)(s + 1) * 8u);
        }

        // flush h history: thread (dt, m, jo) reads uint4, coalesced global
        #pragma unroll
        for (int k = 0; k < 2; ++k) {
            const int c  = tid + k * 512;
            const int dt = c >> 8, m = (c >> 4) & 15, jo = c & 15;
            const int s  = w * WIN + dt;
            const int t  = dir ? (T_ - 1 - s) : s;
            const uint4 v = *(const uint4*)
                &hring[(s + 1) & (RING - 1)][(jo >> 2) * 512 + ((jo & 3) * 16 + m) * 8];
            *(uint4*)(l0h + ((size_t)(b0 + m) * T_ + t) * 256 + dir * H_ + jo * 8) = v;
        }
    }
}

// ---------------------------------------------------------------------------
// xg GEMM (both dirs, grid.z): D[j'][bt] = W_A . l0h_B + bias, emitted in
// scan C-layout: xgC[bg][t][g][jt][lane] as uint2 (4 consecutive j's, bf16).
// blockIdx.x -> bt tile (n, 128; single batch per tile), .y -> j' tile (m).
// ---------------------------------------------------------------------------
__global__ __launch_bounds__(256, 2) void xg_gemm_mfma(
    const bf16* __restrict__ A,
    const float* __restrict__ w_f, const float* __restrict__ w_r,
    const float* __restrict__ bi_f, const float* __restrict__ bi_r,
    const float* __restrict__ bh_f, const float* __restrict__ bh_r,
    bf16* __restrict__ xg_f, bf16* __restrict__ xg_r)
{
    __shared__ short As[128 * 40];   // l0h rows (bt)
    __shared__ short Ws[128 * 40];   // W rows (j')
    __shared__ float Bias_s[128];

    const int dir  = blockIdx.z;
    const float* W   = dir ? w_r : w_f;
    const float* bi  = dir ? bi_r : bi_f;
    const float* bh  = dir ? bh_r : bh_f;
    bf16* xg         = dir ? xg_r : xg_f;

    const int tid  = threadIdx.x;
    const int lane = tid & 63;
    const int wv   = tid >> 6;
    const int col  = lane & 15;
    const int quad = lane >> 4;
    const int n0   = blockIdx.x * 128;        // bt base (single batch)
    const int g    = blockIdx.y;              // j' block = gate
    const int m0   = g * 128;

    if (tid < 128) {
        const int n = m0 + tid;
        Bias_s[tid] = bi[n] + ((n < 2 * H_) ? bh[n] : 0.0f);
    }

    f32x4 acc[2][8];
    #pragma unroll
    for (int mt = 0; mt < 2; ++mt)
        #pragma unroll
        for (int nt = 0; nt < 8; ++nt) acc[mt][nt] = (f32x4){0.f, 0.f, 0.f, 0.f};

    for (int k0 = 0; k0 < 256; k0 += 32) {
        #pragma unroll
        for (int i = 0; i < 2; ++i) {
            const int c = tid + i * 256;
            const int row = c >> 2, q4 = c & 3;
            *(uint4*)&As[row * 40 + q4 * 8] =
                *(const uint4*)(A + (size_t)(n0 + row) * 256 + k0 + q4 * 8);
        }
        #pragma unroll
        for (int i = 0; i < 4; ++i) {
            const int c = tid + i * 256;
            const int row = c >> 3, q = c & 7;
            const float4 v = *(const float4*)(W + (size_t)(m0 + row) * 256 + k0 + q * 4);
            ushort4 u;
            u.x = f2bu(v.x); u.y = f2bu(v.y); u.z = f2bu(v.z); u.w = f2bu(v.w);
            *(ushort4*)&Ws[row * 40 + q * 4] = u;
        }
        __syncthreads();

        s16x8 wfr[2], hfr[8];
        #pragma unroll
        for (int mt = 0; mt < 2; ++mt)
            wfr[mt] = *(const s16x8*)&Ws[(wv * 32 + mt * 16 + col) * 40 + quad * 8];
        #pragma unroll
        for (int nt = 0; nt < 8; ++nt)
            hfr[nt] = *(const s16x8*)&As[(nt * 16 + col) * 40 + quad * 8];

        #pragma unroll
        for (int mt = 0; mt < 2; ++mt)
            #pragma unroll
            for (int nt = 0; nt < 8; ++nt)
                acc[mt][nt] = MFMA16(wfr[mt], hfr[nt], acc[mt][nt]);
        __syncthreads();
    }

    const int batch = n0 >> 11;
    const int bg = batch >> 4, cm = batch & 15;
    #pragma unroll
    for (int mt = 0; mt < 2; ++mt) {
        const int jt = wv * 2 + mt;
        float bv[4];
        #pragma unroll
        for (int r = 0; r < 4; ++r)
            bv[r] = Bias_s[wv * 32 + mt * 16 + quad * 4 + r];
        #pragma unroll
        for (int nt = 0; nt < 8; ++nt) {
            const int t = (n0 & 2047) + nt * 16 + col;
            uint2 o;
            o.x = (unsigned)f2bu(acc[mt][nt][0] + bv[0]) |
                  ((unsigned)f2bu(acc[mt][nt][1] + bv[1]) << 16);
            o.y = (unsigned)f2bu(acc[mt][nt][2] + bv[2]) |
                  ((unsigned)f2bu(acc[mt][nt][3] + bv[3]) << 16);
            const size_t idx = ((((size_t)bg * T_ + t) * 3 + g) * 8 + jt) * 64
                             + quad * 16 + cm;
            ((uint2*)xg)[idx] = o;
        }
    }
}

// ---------------------------------------------------------------------------
// Layer 1 scan: seeds from xgC (3 coalesced uint2/step, window-prefetched).
// ---------------------------------------------------------------------------
__global__ __launch_bounds__(512) void gru_l1_mfma(
    const bf16* __restrict__ xg_f, const bf16* __restrict__ xg_r,
    const float* __restrict__ whh_f, const float* __restrict__ bhh_f,
    const float* __restrict__ whh_r, const float* __restrict__ bhh_r,
    bf16* __restrict__ l1h, int fixed_dir)
{
    __shared__ __align__(16) bf16 hring[RING][2048];
    __shared__ unsigned syncnt;

    const int bx   = blockIdx.x;
    const int dir  = (fixed_dir >= 0) ? fixed_dir : (bx >> 2);
    const int bg   = bx & 3;
    const int b0   = bg * 16;
    const int tid  = threadIdx.x;
    const int lane = tid & 63;
    const int wv   = tid >> 6;
    const int col  = lane & 15;
    const int quad = lane >> 4;

    const bf16*  XG  = dir ? xg_r : xg_f;
    const float* Whh = dir ? whh_r : whh_f;
    const float* Bhh = dir ? bhh_r : bhh_f;

    s16x8 wfr[3][4];
    #pragma unroll
    for (int g = 0; g < 3; ++g) {
        const float* wrow = Whh + (size_t)(g * H_ + wv * 16 + col) * H_;
        #pragma unroll
        for (int kt = 0; kt < 4; ++kt) {
            const float* p = wrow + kt * 32 + quad * 8;
            s16x8 f;
            #pragma unroll
            for (int i = 0; i < 8; ++i) f[i] = f2bs(p[i]);
            wfr[g][kt] = f;
        }
    }
    f32x4 sN;
    #pragma unroll
    for (int r = 0; r < 4; ++r)
        sN[r] = Bhh[2*H_ + wv * 16 + quad * 4 + r];
    const f32x4 z4 = (f32x4){0.f, 0.f, 0.f, 0.f};

    const int wkt  = wv >> 1;
    const int wl   = (((wv << 1) + (quad >> 1)) & 3) * 16 + col;
    const int woff = wkt * 512 + wl * 8 + (quad & 1) * 4;

    for (int i = tid; i < 2048; i += 512) hring[0][i] = __float2bfloat16(0.0f);
    if (tid == 0) syncnt = 0;

    // xgC base: [bg][t][g][jt][lane] uint2
    const uint2* xgb = (const uint2*)XG + ((size_t)bg * T_) * 3 * 8 * 64;
    const int lidx = wv * 64 + lane;   // jt*64 + lane (within [g] slot? no: [jt][lane])

    uint2 xcur[WIN][3], xnxt[WIN][3];
    #pragma unroll
    for (int si = 0; si < WIN; ++si) {
        const int t = dir ? (T_ - 1 - si) : si;
        #pragma unroll
        for (int g = 0; g < 3; ++g)
            xcur[si][g] = xgb[((size_t)t * 3 + g) * 512 + lidx];
    }
    __syncthreads();

    float hprev[4] = {0.f, 0.f, 0.f, 0.f};

    for (int w = 0; w < NW; ++w) {
        #pragma unroll
        for (int si = 0; si < WIN; ++si) {
            const int s  = w * WIN + si;
            const int rb = s & (RING - 1);
            const int wb = (s + 1) & (RING - 1);

            s16x8 hfr[4];
            #pragma unroll
            for (int kt = 0; kt < 4; ++kt)
                hfr[kt] = *(const s16x8*)&hring[rb][kt * 512 + lane * 8];

            // unpack seeds while ds_reads are in flight
            const uint2 xr2 = xcur[si][0], xz2 = xcur[si][1], xn2 = xcur[si][2];
            const f32x4 seedR = (f32x4){
                __uint_as_float(xr2.x << 16), __uint_as_float(xr2.x & 0xffff0000u),
                __uint_as_float(xr2.y << 16), __uint_as_float(xr2.y & 0xffff0000u)};
            const f32x4 seedZ = (f32x4){
                __uint_as_float(xz2.x << 16), __uint_as_float(xz2.x & 0xffff0000u),
                __uint_as_float(xz2.y << 16), __uint_as_float(xz2.y & 0xffff0000u)};
            const float xnf[4] = {
                __uint_as_float(xn2.x << 16), __uint_as_float(xn2.x & 0xffff0000u),
                __uint_as_float(xn2.y << 16), __uint_as_float(xn2.y & 0xffff0000u)};

            f32x4 aR0 = MFMA16(wfr[0][0], hfr[0], seedR);
            f32x4 aZ0 = MFMA16(wfr[1][0], hfr[0], seedZ);
            f32x4 aN0 = MFMA16(wfr[2][0], hfr[0], sN);
            f32x4 aR1 = MFMA16(wfr[0][2], hfr[2], z4);
            f32x4 aZ1 = MFMA16(wfr[1][2], hfr[2], z4);
            f32x4 aN1 = MFMA16(wfr[2][2], hfr[2], z4);
            aR0 = MFMA16(wfr[0][1], hfr[1], aR0);
            aZ0 = MFMA16(wfr[1][1], hfr[1], aZ0);
            aN0 = MFMA16(wfr[2][1], hfr[1], aN0);
            aR1 = MFMA16(wfr[0][3], hfr[3], aR1);
            aZ1 = MFMA16(wfr[1][3], hfr[3], aZ1);
            aN1 = MFMA16(wfr[2][3], hfr[3], aN1);

            if (si == 0 && w + 1 < NW) {
                #pragma unroll
                for (int sj = 0; sj < WIN; ++sj) {
                    const int s2 = (w + 1) * WIN + sj;
                    const int t2 = dir ? (T_ - 1 - s2) : s2;
                    #pragma unroll
                    for (int g = 0; g < 3; ++g)
                        xnxt[sj][g] = xgb[((size_t)t2 * 3 + g) * 512 + lidx];
                }
            }

            unsigned short hb[4];
            #pragma unroll
            for (int r = 0; r < 4; ++r) {
                const float rg = sigf(aR0[r] + aR1[r]);
                const float zg = sigf(aZ0[r] + aZ1[r]);
                const float ng = tanhf_(fmaf(rg, aN0[r] + aN1[r], xnf[r]));
                const float hn = fmaf(zg, hprev[r] - ng, ng);
                hprev[r] = hn;
                hb[r] = f2bu(hn);
            }
            uint2 wv2;
            wv2.x = (unsigned)hb[0] | ((unsigned)hb[1] << 16);
            wv2.y = (unsigned)hb[2] | ((unsigned)hb[3] << 16);
            *(uint2*)&hring[wb][woff] = wv2;

            wave_sync(&syncnt, lane, (unsigned)(s + 1) * 8u);
        }

        #pragma unroll
        for (int k = 0; k < 2; ++k) {
            const int c  = tid + k * 512;
            const int dt = c >> 8, m = (c >> 4) & 15, jo = c & 15;
            const int s  = w * WIN + dt;
            const int t  = dir ? (T_ - 1 - s) : s;
            const uint4 v = *(const uint4*)
                &hring[(s + 1) & (RING - 1)][(jo >> 2) * 512 + ((jo & 3) * 16 + m) * 8];
            *(uint4*)(l1h + ((size_t)(b0 + m) * T_ + t) * 256 + dir * H_ + jo * 8) = v;
        }
        #pragma unroll
        for (int si = 0; si < WIN; ++si) {
            xcur[si][0] = xnxt[si][0];
            xcur[si][1] = xnxt[si][1];
            xcur[si][2] = xnxt[si][2];
        }
    }
}

// ---------------------------------------------------------------------------
// FC epilogue: out[bt][c] = fc_b[c] + fc_w[c][:] . l1h[bt][:]
// ---------------------------------------------------------------------------
__global__ __launch_bounds__(256, 2) void fc_kernel(
    const bf16* __restrict__ h, const float* __restrict__ fcw,
    const float* __restrict__ fcb, float* __restrict__ out)
{
    __shared__ float w0[256], w1[256];
    const int tid = threadIdx.x;
    w0[tid] = fcw[tid];
    w1[tid] = fcw[256 + tid];
    __syncthreads();

    const size_t bt = (size_t)blockIdx.x * 256 + tid;
    const bf16* hp = h + bt * 256;
    float s0 = fcb[0], s1 = fcb[1];
    #pragma unroll 4
    for (int k8 = 0; k8 < 32; ++k8) {
        const uint4 u = *(const uint4*)(hp + k8 * 8);
        const unsigned uu[4] = {u.x, u.y, u.z, u.w};
        #pragma unroll
        for (int p = 0; p < 4; ++p) {
            const float v0 = __uint_as_float(uu[p] << 16);
            const float v1 = __uint_as_float(uu[p] & 0xffff0000u);
            const int k = k8 * 8 + p * 2;
            s0 = fmaf(w0[k], v0, s0);     s1 = fmaf(w1[k], v0, s1);
            s0 = fmaf(w0[k + 1], v1, s0); s1 = fmaf(w1[k + 1], v1, s1);
        }
    }
    out[bt * 2]     = s0;
    out[bt * 2 + 1] = s1;
}

extern "C" void kernel_launch(void* const* d_in, const int* in_sizes, int n_in,
                              void* d_out, int out_size, void* d_ws, size_t ws_size,
                              hipStream_t stream)
{
    if (n_in < 19) return;
    const float* x     = (const float*)d_in[0];
    const float* wih0  = (const float*)d_in[1];
    const float* whh0  = (const float*)d_in[2];
    const float* bih0  = (const float*)d_in[3];
    const float* bhh0  = (const float*)d_in[4];
    const float* wih0r = (const float*)d_in[5];
    const float* whh0r = (const float*)d_in[6];
    const float* bih0r = (const float*)d_in[7];
    const float* bhh0r = (const float*)d_in[8];
    const float* wih1  = (const float*)d_in[9];
    const float* whh1  = (const float*)d_in[10];
    const float* bih1  = (const float*)d_in[11];
    const float* bhh1  = (const float*)d_in[12];
    const float* wih1r = (const float*)d_in[13];
    const float* whh1r = (const float*)d_in[14];
    const float* bih1r = (const float*)d_in[15];
    const float* bhh1r = (const float*)d_in[16];
    const float* fcw   = (const float*)d_in[17];
    const float* fcb   = (const float*)d_in[18];
    float* out = (float*)d_out;

    const size_t nBT  = (size_t)B_ * T_;
    const size_t hh_b = nBT * 2 * H_ * sizeof(bf16);     // 64 MiB
    const size_t xg_b = nBT * G_ * sizeof(bf16);         // 96 MiB per dir
    const size_t xg_el = nBT * G_;

    if (ws_size >= hh_b + 2 * xg_b) {                    // 256 MiB path
        bf16* l0h = (bf16*)d_ws;
        bf16* xgf = (bf16*)((char*)d_ws + hh_b);
        bf16* xgr = xgf + xg_el;

        gru_l0_mfma<<<dim3(8), dim3(512), 0, stream>>>(
            x, wih0, whh0, bih0, bhh0, wih0r, whh0r, bih0r, bhh0r, l0h);
        xg_gemm_mfma<<<dim3(1024, 3, 2), dim3(256), 0, stream>>>(
            l0h, wih1, wih1r, bih1, bih1r, bhh1, bhh1r, xgf, xgr);
        gru_l1_mfma<<<dim3(8), dim3(512), 0, stream>>>(
            xgf, xgr, whh1, bhh1, whh1r, bhh1r, l0h, -1);   // l1h aliases l0h
        fc_kernel<<<dim3((int)(nBT / 256)), dim3(256), 0, stream>>>(l0h, fcw, fcb, out);
    } else if (ws_size >= 2 * hh_b + xg_b) {             // 224 MiB sequential
        bf16* l0h = (bf16*)d_ws;
        bf16* xg  = (bf16*)((char*)d_ws + hh_b);
        bf16* l1h = (bf16*)((char*)d_ws + hh_b + xg_b);

        gru_l0_mfma<<<dim3(8), dim3(512), 0, stream>>>(
            x, wih0, whh0, bih0, bhh0, wih0r, whh0r, bih0r, bhh0r, l0h);
        xg_gemm_mfma<<<dim3(1024, 3, 1), dim3(256), 0, stream>>>(
            l0h, wih1, wih1, bih1, bih1, bhh1, bhh1, xg, xg);
        gru_l1_mfma<<<dim3(4), dim3(512), 0, stream>>>(
            xg, xg, whh1, bhh1, whh1r, bhh1r, l1h, 0);
        xg_gemm_mfma<<<dim3(1024, 3, 1), dim3(256), 0, stream>>>(
            l0h, wih1r, wih1r, bih1r, bih1r, bhh1r, bhh1r, xg, xg);
        gru_l1_mfma<<<dim3(4), dim3(512), 0, stream>>>(
            xg, xg, whh1, bhh1, whh1r, bhh1r, l1h, 1);
        fc_kernel<<<dim3((int)(nBT / 256)), dim3(256), 0, stream>>>(l1h, fcw, fcb, out);
    }
}